// Round 2
// baseline (376.554 us; speedup 1.0000x reference)
//
#include <hip/hip_runtime.h>
#include <hip/hip_bf16.h>

// Problem constants
#define BATCH     512
#define IMG       128
#define PS        8
#define GRID_P    16      // IMG/PS
#define NP        256     // GRID_P*GRID_P
#define C         128     // BOND_DIM
#define R         64      // CP_RANK
#define E         512     // EMBED_DIM

// ---------------------------------------------------------------------------
// Kernel 1: patchify + patch embed + pos add
//   h0[b, p, c] = sum_k patch(b,p,k) * Wp[k,c] + bp[c] + pos[p,c]
// block = (b, gy): one image-row of 16 patches. 256 threads = 128 c x 2 halves
// ---------------------------------------------------------------------------
__global__ __launch_bounds__(256) void patch_embed_kernel(
    const float* __restrict__ x,     // (B,1,128,128)
    const float* __restrict__ Wp,    // (64,128)
    const float* __restrict__ bp,    // (128)
    const float* __restrict__ pos,   // (1,256,128)
    float* __restrict__ h0)          // (B,256,128)
{
    __shared__ __align__(16) float pix[PS * IMG];   // 8 rows x 128 cols = 4 KB
    const int bi = blockIdx.x;
    const int b  = bi >> 4;
    const int gy = bi & 15;
    const int t  = threadIdx.x;

    // cooperative load of 8 pixel rows (1024 floats) via float4
    {
        const float4* src = (const float4*)(x + ((size_t)b * IMG + gy * PS) * IMG);
        ((float4*)pix)[t] = src[t];
    }
    __syncthreads();

    const int c    = t & 127;
    const int half = t >> 7;          // which 8 gx's this thread owns

    float acc[8];
#pragma unroll
    for (int g = 0; g < 8; ++g) {
        const int gx = half * 8 + g;
        acc[g] = bp[c] + pos[(gy * GRID_P + gx) * C + c];
    }

    for (int py = 0; py < PS; ++py) {
#pragma unroll
        for (int px0 = 0; px0 < PS; px0 += 4) {
            const int k0 = py * PS + px0;
            const float w0 = Wp[(k0 + 0) * C + c];
            const float w1 = Wp[(k0 + 1) * C + c];
            const float w2 = Wp[(k0 + 2) * C + c];
            const float w3 = Wp[(k0 + 3) * C + c];
#pragma unroll
            for (int g = 0; g < 8; ++g) {
                const int gx = half * 8 + g;
                const float4 p4 = *((const float4*)(pix + py * IMG + gx * PS + px0));
                acc[g] += p4.x * w0 + p4.y * w1 + p4.z * w2 + p4.w * w3;
            }
        }
    }

#pragma unroll
    for (int g = 0; g < 8; ++g) {
        const int gx = half * 8 + g;
        h0[((size_t)b * NP + gy * GRID_P + gx) * C + c] = acc[g];
    }
}

// ---------------------------------------------------------------------------
// Kernel 2 (templated per level): quad-group + CP contraction
//   u[b,n,q,r] = sum_c x[b,n,q,c] * f[n,q,c,r]
//   p[b,n,r]   = prod_q u[b,n,q,r]
//   out[b,n,c] = sum_r p[b,n,r] * o[n,r,c]
// block = (node n, tile of TB batches). 256 threads.
// v2: no xs LDS staging (u-phase x loads are wave-broadcast global loads),
//     LDS = us+ps only (20 KB max), 2 barriers per tile, grid oversubscribed.
// ---------------------------------------------------------------------------
template<int NN, int GIN, int TB>
__global__ __launch_bounds__(256, 4) void cp_level_kernel(
    const float* __restrict__ hin,   // (B, GIN*GIN, C)
    const float* __restrict__ f,     // (NN, 4, C, R)
    const float* __restrict__ o,     // (NN, R, C)
    float* __restrict__ hout)        // (B, NN, C)
{
    constexpr int G2  = GIN / 2;
    constexpr int NIN = GIN * GIN;
    constexpr int BH  = TB / 2;      // batches per o-phase thread

    __shared__ __align__(16) float us[4 * TB * R];  // 16 KB @ TB=16
    __shared__ __align__(16) float ps[TB * R];      // 4 KB  @ TB=16

    const int bi  = blockIdx.x;
    const int n   = bi % NN;
    const int bt0 = (bi / NN) * TB;
    const int y1 = n / G2, x1 = n % G2;
    const int t    = threadIdx.x;
    const int wave = t >> 6;         // = q in u-phase
    const int lane = t & 63;         // = r in u-phase

    // ---- u-phase: wave = q, lane = r; TB batch accumulators ----
    {
        const int q = wave, r = lane;
        const int y0 = q >> 1, x0 = q & 1;
        const int pidx = (2 * y1 + y0) * GIN + (2 * x1 + x0);
        const float* xq = hin + ((size_t)bt0 * NIN + pidx) * C;
        const float* fq = f + ((size_t)(n * 4 + q) * C) * R + r;

        float acc[TB];
#pragma unroll
        for (int b = 0; b < TB; ++b) acc[b] = 0.f;

        for (int c0 = 0; c0 < C; c0 += 4) {
            float4 xv[TB];
#pragma unroll
            for (int b = 0; b < TB; ++b)
                xv[b] = *((const float4*)(xq + (size_t)b * NIN * C + c0));
            const float f0 = fq[(c0 + 0) * R];
            const float f1 = fq[(c0 + 1) * R];
            const float f2 = fq[(c0 + 2) * R];
            const float f3 = fq[(c0 + 3) * R];
#pragma unroll
            for (int b = 0; b < TB; ++b)
                acc[b] += xv[b].x * f0 + xv[b].y * f1 + xv[b].z * f2 + xv[b].w * f3;
        }
#pragma unroll
        for (int b = 0; b < TB; ++b) us[(q * TB + b) * R + r] = acc[b];
    }
    __syncthreads();

    // ---- p-phase: product over 4 quadrants, TB*R (b,r) pairs ----
#pragma unroll
    for (int k = 0; k < (TB * R) / 256; ++k) {
        const int idx = t + 256 * k;
        const int b = idx >> 6, r = idx & 63;
        ps[idx] = us[(0 * TB + b) * R + r] * us[(1 * TB + b) * R + r]
                * us[(2 * TB + b) * R + r] * us[(3 * TB + b) * R + r];
    }
    __syncthreads();

    // ---- o-phase: out[b,c] = sum_r p[b,r]*o[n,r,c]; thread = (c, BH b's) ----
    {
        const int c  = t & 127;
        const int bg = t >> 7;
        float acc[BH];
#pragma unroll
        for (int i = 0; i < BH; ++i) acc[i] = 0.f;
        const float* oc = o + (size_t)n * R * C + c;
        for (int r0 = 0; r0 < R; r0 += 4) {
            const float o0 = oc[(r0 + 0) * C];
            const float o1 = oc[(r0 + 1) * C];
            const float o2 = oc[(r0 + 2) * C];
            const float o3 = oc[(r0 + 3) * C];
#pragma unroll
            for (int i = 0; i < BH; ++i) {
                const int b = bg * BH + i;
                const float4 pv = *((const float4*)(ps + b * R + r0));
                acc[i] += pv.x * o0 + pv.y * o1 + pv.z * o2 + pv.w * o3;
            }
        }
#pragma unroll
        for (int i = 0; i < BH; ++i) {
            const int b = bg * BH + i;
            hout[((size_t)(bt0 + b) * NN + n) * C + c] = acc[i];
        }
    }
}

// ---------------------------------------------------------------------------
// Kernel 3: LayerNorm + head GEMV + L2 normalize. block = one batch row.
// ---------------------------------------------------------------------------
__global__ __launch_bounds__(256) void head_kernel(
    const float* __restrict__ h,     // (B, 1, 128)
    const float* __restrict__ gamma, const float* __restrict__ beta,
    const float* __restrict__ Wh,    // (128, 512)
    const float* __restrict__ bh,    // (512)
    float* __restrict__ out)         // (B, 512)
{
    const int b = blockIdx.x;
    const int t = threadIdx.x;
    const int lane = t & 63, wave = t >> 6;
    __shared__ __align__(16) float hn[C];
    __shared__ float red1[4], red2[4], red3[4];

    float v = 0.f;
    if (t < C) v = h[(size_t)b * C + t];
    float s = v, ss = v * v;
#pragma unroll
    for (int off = 32; off >= 1; off >>= 1) {
        s  += __shfl_down(s, off);
        ss += __shfl_down(ss, off);
    }
    if (lane == 0) { red1[wave] = s; red2[wave] = ss; }
    __syncthreads();
    const float sum   = red1[0] + red1[1] + red1[2] + red1[3];
    const float sumsq = red2[0] + red2[1] + red2[2] + red2[3];
    const float mu   = sum * (1.f / C);
    const float var  = sumsq * (1.f / C) - mu * mu;
    const float rstd = rsqrtf(var + 1e-5f);
    if (t < C) hn[t] = (v - mu) * rstd * gamma[t] + beta[t];
    __syncthreads();

    float acc0 = bh[t], acc1 = bh[t + 256];
    for (int c0 = 0; c0 < C; c0 += 4) {
        const float4 hv = *((const float4*)(hn + c0));
        const float* w  = Wh + (size_t)c0 * E + t;
        acc0 += hv.x * w[0] + hv.y * w[E] + hv.z * w[2 * E] + hv.w * w[3 * E];
        const float* w2 = w + 256;
        acc1 += hv.x * w2[0] + hv.y * w2[E] + hv.z * w2[2 * E] + hv.w * w2[3 * E];
    }

    float sq = acc0 * acc0 + acc1 * acc1;
#pragma unroll
    for (int off = 32; off >= 1; off >>= 1) sq += __shfl_down(sq, off);
    if (lane == 0) red3[wave] = sq;
    __syncthreads();
    float nrm = sqrtf(red3[0] + red3[1] + red3[2] + red3[3]);
    nrm = fmaxf(nrm, 1e-12f);
    const float inv = 1.f / nrm;
    out[(size_t)b * E + t]       = acc0 * inv;
    out[(size_t)b * E + t + 256] = acc1 * inv;
}

// ---------------------------------------------------------------------------
extern "C" void kernel_launch(void* const* d_in, const int* in_sizes, int n_in,
                              void* d_out, int out_size, void* d_ws, size_t ws_size,
                              hipStream_t stream) {
    const float* x     = (const float*)d_in[0];
    const float* Wp    = (const float*)d_in[1];
    const float* bp    = (const float*)d_in[2];
    const float* pos   = (const float*)d_in[3];
    const float* gamma = (const float*)d_in[4];
    const float* beta  = (const float*)d_in[5];
    const float* Wh    = (const float*)d_in[6];
    const float* bh    = (const float*)d_in[7];
    const float* f0    = (const float*)d_in[8];
    const float* o0    = (const float*)d_in[9];
    const float* f1    = (const float*)d_in[10];
    const float* o1    = (const float*)d_in[11];
    const float* f2    = (const float*)d_in[12];
    const float* o2    = (const float*)d_in[13];
    const float* f3    = (const float*)d_in[14];
    const float* o3    = (const float*)d_in[15];
    float* out = (float*)d_out;

    float* h0 = (float*)d_ws;                      // (512,256,128) = 64 MiB
    float* h1 = h0 + (size_t)BATCH * NP * C;       // (512, 64,128) = 16 MiB
    float* h2 = h1 + (size_t)BATCH * 64 * C;       // (512, 16,128) =  4 MiB
    float* h3 = h2 + (size_t)BATCH * 16 * C;       // (512,  4,128) =  1 MiB
    float* h4 = h3 + (size_t)BATCH * 4 * C;        // (512,  1,128) = 256 KiB

    patch_embed_kernel<<<BATCH * GRID_P, 256, 0, stream>>>(x, Wp, bp, pos, h0);

    // grid = NN * (BATCH/TB): 2048 / 1024 / 256 / 64 blocks
    cp_level_kernel<64, 16, 16><<<64 * (BATCH / 16), 256, 0, stream>>>(h0, f0, o0, h1);
    cp_level_kernel<16,  8,  8><<<16 * (BATCH /  8), 256, 0, stream>>>(h1, f1, o1, h2);
    cp_level_kernel< 4,  4,  8><<< 4 * (BATCH /  8), 256, 0, stream>>>(h2, f2, o2, h3);
    cp_level_kernel< 1,  2,  8><<< 1 * (BATCH /  8), 256, 0, stream>>>(h3, f3, o3, h4);

    head_kernel<<<BATCH, 256, 0, stream>>>(h4, gamma, beta, Wh, bh, out);
}

// Round 3
// 221.964 us; speedup vs baseline: 1.6965x; 1.6965x over previous
//
#include <hip/hip_runtime.h>
#include <hip/hip_bf16.h>

// Problem constants
#define BATCH     512
#define IMG       128
#define PS        8
#define GRID_P    16      // IMG/PS
#define NP        256     // GRID_P*GRID_P
#define C         128     // BOND_DIM
#define R         64      // CP_RANK
#define E         512     // EMBED_DIM

typedef float f32x4 __attribute__((ext_vector_type(4)));
typedef short s16x8 __attribute__((ext_vector_type(8)));

__device__ __forceinline__ unsigned short f2bf(float x) {
    unsigned int u = __float_as_uint(x);
    u += 0x7fffu + ((u >> 16) & 1u);          // RNE
    return (unsigned short)(u >> 16);
}
__device__ __forceinline__ float bf2f(unsigned short h) {
    return __uint_as_float(((unsigned int)h) << 16);
}

// ---------------------------------------------------------------------------
// Transpose+convert f (levels 0..3): slices of (C=128 x R=64) fp32 ->
// fT slices (R=64 x C=128) bf16. 340 slices total, contiguous in fT.
// ---------------------------------------------------------------------------
__global__ __launch_bounds__(256) void f_transpose_kernel(
    const float* __restrict__ f0, const float* __restrict__ f1,
    const float* __restrict__ f2, const float* __restrict__ f3,
    unsigned short* __restrict__ fT)
{
    __shared__ float ls[128 * 68];
    const int bi = blockIdx.x, t = threadIdx.x;
    const float* src;
    if      (bi < 256) src = f0 + (size_t)bi * 8192;
    else if (bi < 320) src = f1 + (size_t)(bi - 256) * 8192;
    else if (bi < 336) src = f2 + (size_t)(bi - 320) * 8192;
    else               src = f3 + (size_t)(bi - 336) * 8192;
    unsigned short* dst = fT + (size_t)bi * 8192;

#pragma unroll
    for (int i = 0; i < 8; ++i) {
        const int fi = (t + 256 * i) * 4;
        const int c = fi >> 6, r = fi & 63;          // in[c][r]
        *(float4*)(ls + c * 68 + r) = *(const float4*)(src + fi);
    }
    __syncthreads();
    const int rr = t >> 2, seg = t & 3;              // out row rr (r), 4 thr/row
    unsigned int* d32 = (unsigned int*)(dst + rr * 128 + seg * 32);
#pragma unroll
    for (int ii = 0; ii < 16; ++ii) {
        const int c = seg * 32 + ii * 2;
        const unsigned int lo = f2bf(ls[c * 68 + rr]);
        const unsigned int hi = f2bf(ls[(c + 1) * 68 + rr]);
        d32[ii] = lo | (hi << 16);
    }
}

// ---------------------------------------------------------------------------
// Transpose+convert o (levels 0..3): slices (R=64 x C=128) fp32 ->
// oT slices (C=128 x R=64) bf16. 85 slices total.
// ---------------------------------------------------------------------------
__global__ __launch_bounds__(256) void o_transpose_kernel(
    const float* __restrict__ o0, const float* __restrict__ o1,
    const float* __restrict__ o2, const float* __restrict__ o3,
    unsigned short* __restrict__ oT)
{
    __shared__ float ls[64 * 132];
    const int bi = blockIdx.x, t = threadIdx.x;
    const float* src;
    if      (bi < 64) src = o0 + (size_t)bi * 8192;
    else if (bi < 80) src = o1 + (size_t)(bi - 64) * 8192;
    else if (bi < 84) src = o2 + (size_t)(bi - 80) * 8192;
    else              src = o3 + (size_t)(bi - 84) * 8192;
    unsigned short* dst = oT + (size_t)bi * 8192;

#pragma unroll
    for (int i = 0; i < 8; ++i) {
        const int fi = (t + 256 * i) * 4;
        const int r = fi >> 7, c = fi & 127;         // in[r][c]
        *(float4*)(ls + r * 132 + c) = *(const float4*)(src + fi);
    }
    __syncthreads();
    const int cc = t >> 1, seg = t & 1;              // out row cc (c), 2 thr/row
    unsigned int* d32 = (unsigned int*)(dst + cc * 64 + seg * 32);
#pragma unroll
    for (int ii = 0; ii < 16; ++ii) {
        const int r = seg * 32 + ii * 2;
        const unsigned int lo = f2bf(ls[r * 132 + cc]);
        const unsigned int hi = f2bf(ls[(r + 1) * 132 + cc]);
        d32[ii] = lo | (hi << 16);
    }
}

// ---------------------------------------------------------------------------
// Kernel 1: patchify + patch embed + pos add -> h0 bf16
// ---------------------------------------------------------------------------
__global__ __launch_bounds__(256) void patch_embed_kernel(
    const float* __restrict__ x,     // (B,1,128,128)
    const float* __restrict__ Wp,    // (64,128)
    const float* __restrict__ bp,    // (128)
    const float* __restrict__ pos,   // (1,256,128)
    unsigned short* __restrict__ h0) // (B,256,128) bf16
{
    __shared__ __align__(16) float pix[PS * IMG];
    const int bi = blockIdx.x;
    const int b  = bi >> 4;
    const int gy = bi & 15;
    const int t  = threadIdx.x;

    {
        const float4* src = (const float4*)(x + ((size_t)b * IMG + gy * PS) * IMG);
        ((float4*)pix)[t] = src[t];
    }
    __syncthreads();

    const int c    = t & 127;
    const int half = t >> 7;

    float acc[8];
#pragma unroll
    for (int g = 0; g < 8; ++g) {
        const int gx = half * 8 + g;
        acc[g] = bp[c] + pos[(gy * GRID_P + gx) * C + c];
    }

    for (int py = 0; py < PS; ++py) {
#pragma unroll
        for (int px0 = 0; px0 < PS; px0 += 4) {
            const int k0 = py * PS + px0;
            const float w0 = Wp[(k0 + 0) * C + c];
            const float w1 = Wp[(k0 + 1) * C + c];
            const float w2 = Wp[(k0 + 2) * C + c];
            const float w3 = Wp[(k0 + 3) * C + c];
#pragma unroll
            for (int g = 0; g < 8; ++g) {
                const int gx = half * 8 + g;
                const float4 p4 = *((const float4*)(pix + py * IMG + gx * PS + px0));
                acc[g] += p4.x * w0 + p4.y * w1 + p4.z * w2 + p4.w * w3;
            }
        }
    }

#pragma unroll
    for (int g = 0; g < 8; ++g) {
        const int gx = half * 8 + g;
        h0[((size_t)b * NP + gy * GRID_P + gx) * C + c] = f2bf(acc[g]);
    }
}

// ---------------------------------------------------------------------------
// Kernel 2 (MFMA): quad-group + CP contraction, bf16 in/out.
// Block = (node n, tile of 64 batches); wave w owns 16 batches end-to-end:
//   u-phase: 4 GEMMs (16b x 128c)@(128c x 64r), A-frags direct from global h,
//            B-frags direct from global fT (16B/lane contiguous).
//   p-phase: elementwise product of the four u-accs in registers (same C-layout).
//   LDS roundtrip: p -> bf16 A-frags (per-wave private 2.3 KB, no barrier).
//   o-phase: (16b x 64r)@(64r x 128c) from oT.
// ---------------------------------------------------------------------------
template<int NN, int GIN>
__global__ __launch_bounds__(256) void cp_level_mfma(
    const unsigned short* __restrict__ hin,  // (B, GIN*GIN, C) bf16
    const unsigned short* __restrict__ fT,   // (NN, 4, R, C) bf16
    const unsigned short* __restrict__ oT,   // (NN, C, R) bf16
    unsigned short* __restrict__ hout)       // (B, NN, C) bf16
{
    constexpr int NIN = GIN * GIN;
    constexpr int G2  = GIN / 2;
    constexpr int PSTR = 72;                 // p row stride (2-byte el), 144 B

    __shared__ unsigned short ps[4][16 * PSTR];   // per-wave private

    const int n     = blockIdx.x % NN;
    const int btile = blockIdx.x / NN;
    const int t = threadIdx.x, w = t >> 6, lane = t & 63;
    const int m = lane & 15, g = lane >> 4;
    const int bt = btile * 64 + w * 16;
    const int y1 = n / G2, x1 = n % G2;

    f32x4 acc_u[4][4];
#pragma unroll
    for (int q = 0; q < 4; ++q)
#pragma unroll
        for (int nt = 0; nt < 4; ++nt) acc_u[q][nt] = (f32x4){0.f, 0.f, 0.f, 0.f};

    const unsigned short* fTn = fT + (size_t)n * 4 * R * C;

#pragma unroll
    for (int q = 0; q < 4; ++q) {
        const int pidx = (2 * y1 + (q >> 1)) * GIN + 2 * x1 + (q & 1);
        const unsigned short* xq = hin + ((size_t)(bt + m) * NIN + pidx) * C;
        const unsigned short* fq = fTn + (size_t)q * R * C;
#pragma unroll
        for (int kt = 0; kt < 4; ++kt) {
            const int koff = kt * 32 + g * 8;
            const s16x8 a = *(const s16x8*)(xq + koff);
#pragma unroll
            for (int nt = 0; nt < 4; ++nt) {
                const s16x8 b = *(const s16x8*)(fq + (size_t)(nt * 16 + m) * C + koff);
                acc_u[q][nt] = __builtin_amdgcn_mfma_f32_16x16x32_bf16(a, b, acc_u[q][nt], 0, 0, 0);
            }
        }
    }

    // p-phase: elementwise product across q (identical C-layout)
    f32x4 p[4];
#pragma unroll
    for (int nt = 0; nt < 4; ++nt)
        p[nt] = acc_u[0][nt] * acc_u[1][nt] * acc_u[2][nt] * acc_u[3][nt];

    // stage p to per-wave LDS as bf16, rows = local b (0..15), cols = r (0..63)
    unsigned short* myps = &ps[w][0];
#pragma unroll
    for (int nt = 0; nt < 4; ++nt)
#pragma unroll
        for (int j = 0; j < 4; ++j)
            myps[(g * 4 + j) * PSTR + nt * 16 + m] = f2bf(p[nt][j]);

    // o-phase
    f32x4 acc_o[8];
#pragma unroll
    for (int ct = 0; ct < 8; ++ct) acc_o[ct] = (f32x4){0.f, 0.f, 0.f, 0.f};

    const unsigned short* oTn = oT + (size_t)n * C * R;
#pragma unroll
    for (int kt = 0; kt < 2; ++kt) {
        const int koff = kt * 32 + g * 8;
        const s16x8 a = *(const s16x8*)(myps + m * PSTR + koff);
#pragma unroll
        for (int ct = 0; ct < 8; ++ct) {
            const s16x8 b = *(const s16x8*)(oTn + (size_t)(ct * 16 + m) * R + koff);
            acc_o[ct] = __builtin_amdgcn_mfma_f32_16x16x32_bf16(a, b, acc_o[ct], 0, 0, 0);
        }
    }

    // store: row b = bt + g*4 + j, col c = ct*16 + m
#pragma unroll
    for (int ct = 0; ct < 8; ++ct)
#pragma unroll
        for (int j = 0; j < 4; ++j) {
            const int row = bt + g * 4 + j;
            hout[((size_t)row * NN + n) * C + ct * 16 + m] = f2bf(acc_o[ct][j]);
        }
}

// ---------------------------------------------------------------------------
// Kernel 3: LayerNorm + head GEMV + L2 normalize (h4 bf16 -> out fp32)
// ---------------------------------------------------------------------------
__global__ __launch_bounds__(256) void head_kernel(
    const unsigned short* __restrict__ h,   // (B, 1, 128) bf16
    const float* __restrict__ gamma, const float* __restrict__ beta,
    const float* __restrict__ Wh,    // (128, 512)
    const float* __restrict__ bh,    // (512)
    float* __restrict__ out)         // (B, 512)
{
    const int b = blockIdx.x;
    const int t = threadIdx.x;
    const int lane = t & 63, wave = t >> 6;
    __shared__ __align__(16) float hn[C];
    __shared__ float red1[4], red2[4], red3[4];

    float v = 0.f;
    if (t < C) v = bf2f(h[(size_t)b * C + t]);
    float s = v, ss = v * v;
#pragma unroll
    for (int off = 32; off >= 1; off >>= 1) {
        s  += __shfl_down(s, off);
        ss += __shfl_down(ss, off);
    }
    if (lane == 0) { red1[wave] = s; red2[wave] = ss; }
    __syncthreads();
    const float sum   = red1[0] + red1[1] + red1[2] + red1[3];
    const float sumsq = red2[0] + red2[1] + red2[2] + red2[3];
    const float mu   = sum * (1.f / C);
    const float var  = sumsq * (1.f / C) - mu * mu;
    const float rstd = rsqrtf(var + 1e-5f);
    if (t < C) hn[t] = (v - mu) * rstd * gamma[t] + beta[t];
    __syncthreads();

    float acc0 = bh[t], acc1 = bh[t + 256];
    for (int c0 = 0; c0 < C; c0 += 4) {
        const float4 hv = *((const float4*)(hn + c0));
        const float* wgt = Wh + (size_t)c0 * E + t;
        acc0 += hv.x * wgt[0] + hv.y * wgt[E] + hv.z * wgt[2 * E] + hv.w * wgt[3 * E];
        const float* w2 = wgt + 256;
        acc1 += hv.x * w2[0] + hv.y * w2[E] + hv.z * w2[2 * E] + hv.w * w2[3 * E];
    }

    float sq = acc0 * acc0 + acc1 * acc1;
#pragma unroll
    for (int off = 32; off >= 1; off >>= 1) sq += __shfl_down(sq, off);
    if (lane == 0) red3[wave] = sq;
    __syncthreads();
    float nrm = sqrtf(red3[0] + red3[1] + red3[2] + red3[3]);
    nrm = fmaxf(nrm, 1e-12f);
    const float inv = 1.f / nrm;
    out[(size_t)b * E + t]       = acc0 * inv;
    out[(size_t)b * E + t + 256] = acc1 * inv;
}

// ---------------------------------------------------------------------------
extern "C" void kernel_launch(void* const* d_in, const int* in_sizes, int n_in,
                              void* d_out, int out_size, void* d_ws, size_t ws_size,
                              hipStream_t stream) {
    const float* x     = (const float*)d_in[0];
    const float* Wp    = (const float*)d_in[1];
    const float* bp    = (const float*)d_in[2];
    const float* pos   = (const float*)d_in[3];
    const float* gamma = (const float*)d_in[4];
    const float* beta  = (const float*)d_in[5];
    const float* Wh    = (const float*)d_in[6];
    const float* bh    = (const float*)d_in[7];
    const float* f0    = (const float*)d_in[8];
    const float* o0    = (const float*)d_in[9];
    const float* f1    = (const float*)d_in[10];
    const float* o1    = (const float*)d_in[11];
    const float* f2    = (const float*)d_in[12];
    const float* o2    = (const float*)d_in[13];
    const float* f3    = (const float*)d_in[14];
    const float* o3    = (const float*)d_in[15];
    float* out = (float*)d_out;

    // workspace layout (bf16 elements)
    unsigned short* h0 = (unsigned short*)d_ws;            // 16,777,216
    unsigned short* h1 = h0 + (size_t)16777216;            //  4,194,304
    unsigned short* h2 = h1 + (size_t)4194304;             //  1,048,576
    unsigned short* h3 = h2 + (size_t)1048576;             //    262,144
    unsigned short* h4 = h3 + (size_t)262144;              //     65,536
    unsigned short* fT = h4 + (size_t)65536;               //  2,785,280 (340 slices)
    unsigned short* oT = fT + (size_t)2785280;             //    696,320 (85 slices)

    unsigned short* fT0 = fT;
    unsigned short* fT1 = fT + (size_t)256 * 8192;
    unsigned short* fT2 = fT + (size_t)320 * 8192;
    unsigned short* fT3 = fT + (size_t)336 * 8192;
    unsigned short* oT0 = oT;
    unsigned short* oT1 = oT + (size_t)64 * 8192;
    unsigned short* oT2 = oT + (size_t)80 * 8192;
    unsigned short* oT3 = oT + (size_t)84 * 8192;

    f_transpose_kernel<<<340, 256, 0, stream>>>(f0, f1, f2, f3, fT);
    o_transpose_kernel<<< 85, 256, 0, stream>>>(o0, o1, o2, o3, oT);

    patch_embed_kernel<<<BATCH * GRID_P, 256, 0, stream>>>(x, Wp, bp, pos, h0);

    cp_level_mfma<64, 16><<<64 * 8, 256, 0, stream>>>(h0, fT0, oT0, h1);
    cp_level_mfma<16,  8><<<16 * 8, 256, 0, stream>>>(h1, fT1, oT1, h2);
    cp_level_mfma< 4,  4><<< 4 * 8, 256, 0, stream>>>(h2, fT2, oT2, h3);
    cp_level_mfma< 1,  2><<< 1 * 8, 256, 0, stream>>>(h3, fT3, oT3, h4);

    head_kernel<<<BATCH, 256, 0, stream>>>(h4, gamma, beta, Wh, bh, out);
}

// Round 4
// 193.150 us; speedup vs baseline: 1.9495x; 1.1492x over previous
//
#include <hip/hip_runtime.h>
#include <hip/hip_bf16.h>

// Problem constants
#define BATCH     512
#define IMG       128
#define PS        8
#define GRID_P    16      // IMG/PS
#define NP        256     // GRID_P*GRID_P
#define C         128     // BOND_DIM
#define R         64      // CP_RANK
#define E         512     // EMBED_DIM

typedef float f32x4 __attribute__((ext_vector_type(4)));
typedef short s16x8 __attribute__((ext_vector_type(8)));

__device__ __forceinline__ unsigned short f2bf(float x) {
    unsigned int u = __float_as_uint(x);
    u += 0x7fffu + ((u >> 16) & 1u);          // RNE
    return (unsigned short)(u >> 16);
}
__device__ __forceinline__ float bf2f(unsigned short h) {
    return __uint_as_float(((unsigned int)h) << 16);
}

// ---------------------------------------------------------------------------
// Tiny pre-pass: WpT[c][k] bf16 (128 x 64) from Wp[k][c] fp32 (64 x 128),
// and pb[p][c] = bp[c] + pos[p][c] fp32 (256 x 128).
// ---------------------------------------------------------------------------
__global__ __launch_bounds__(256) void wpt_pb_kernel(
    const float* __restrict__ Wp, const float* __restrict__ bp,
    const float* __restrict__ pos,
    unsigned short* __restrict__ WpT, float* __restrict__ pb)
{
    const int bi = blockIdx.x, t = threadIdx.x;
    if (bi == 32) {
        // WpT: thread t -> row c = t>>1, half seg = t&1 (32 k's)
        const int c = t >> 1, seg = t & 1;
        unsigned int* d32 = (unsigned int*)(WpT + c * 64 + seg * 32);
#pragma unroll
        for (int i = 0; i < 16; ++i) {
            const int k = seg * 32 + i * 2;
            const unsigned int lo = f2bf(Wp[k * C + c]);
            const unsigned int hi = f2bf(Wp[(k + 1) * C + c]);
            d32[i] = lo | (hi << 16);
        }
    } else {
        const int idx = (bi * 256 + t) * 4;          // 32 blocks cover 32768 floats
        const int c0 = idx & 127;
        const float4 bp4 = *(const float4*)(bp + c0);
        const float4 po4 = *(const float4*)(pos + idx);
        float4 r; r.x = po4.x + bp4.x; r.y = po4.y + bp4.y;
        r.z = po4.z + bp4.z; r.w = po4.w + bp4.w;
        *(float4*)(pb + idx) = r;
    }
}

// ---------------------------------------------------------------------------
// Transpose+convert f (levels 0..3): slices of (C=128 x R=64) fp32 ->
// fT slices (R=64 x C=128) bf16. 340 slices total, contiguous in fT.
// ---------------------------------------------------------------------------
__global__ __launch_bounds__(256) void f_transpose_kernel(
    const float* __restrict__ f0, const float* __restrict__ f1,
    const float* __restrict__ f2, const float* __restrict__ f3,
    unsigned short* __restrict__ fT)
{
    __shared__ float ls[128 * 68];
    const int bi = blockIdx.x, t = threadIdx.x;
    const float* src;
    if      (bi < 256) src = f0 + (size_t)bi * 8192;
    else if (bi < 320) src = f1 + (size_t)(bi - 256) * 8192;
    else if (bi < 336) src = f2 + (size_t)(bi - 320) * 8192;
    else               src = f3 + (size_t)(bi - 336) * 8192;
    unsigned short* dst = fT + (size_t)bi * 8192;

#pragma unroll
    for (int i = 0; i < 8; ++i) {
        const int fi = (t + 256 * i) * 4;
        const int c = fi >> 6, r = fi & 63;          // in[c][r]
        *(float4*)(ls + c * 68 + r) = *(const float4*)(src + fi);
    }
    __syncthreads();
    const int rr = t >> 2, seg = t & 3;              // out row rr (r), 4 thr/row
    unsigned int* d32 = (unsigned int*)(dst + rr * 128 + seg * 32);
#pragma unroll
    for (int ii = 0; ii < 16; ++ii) {
        const int c = seg * 32 + ii * 2;
        const unsigned int lo = f2bf(ls[c * 68 + rr]);
        const unsigned int hi = f2bf(ls[(c + 1) * 68 + rr]);
        d32[ii] = lo | (hi << 16);
    }
}

// ---------------------------------------------------------------------------
// Transpose+convert o (levels 0..3): slices (R=64 x C=128) fp32 ->
// oT slices (C=128 x R=64) bf16. 85 slices total.
// ---------------------------------------------------------------------------
__global__ __launch_bounds__(256) void o_transpose_kernel(
    const float* __restrict__ o0, const float* __restrict__ o1,
    const float* __restrict__ o2, const float* __restrict__ o3,
    unsigned short* __restrict__ oT)
{
    __shared__ float ls[64 * 132];
    const int bi = blockIdx.x, t = threadIdx.x;
    const float* src;
    if      (bi < 64) src = o0 + (size_t)bi * 8192;
    else if (bi < 80) src = o1 + (size_t)(bi - 64) * 8192;
    else if (bi < 84) src = o2 + (size_t)(bi - 80) * 8192;
    else              src = o3 + (size_t)(bi - 84) * 8192;
    unsigned short* dst = oT + (size_t)bi * 8192;

#pragma unroll
    for (int i = 0; i < 8; ++i) {
        const int fi = (t + 256 * i) * 4;
        const int r = fi >> 7, c = fi & 127;         // in[r][c]
        *(float4*)(ls + r * 132 + c) = *(const float4*)(src + fi);
    }
    __syncthreads();
    const int cc = t >> 1, seg = t & 1;              // out row cc (c), 2 thr/row
    unsigned int* d32 = (unsigned int*)(dst + cc * 64 + seg * 32);
#pragma unroll
    for (int ii = 0; ii < 16; ++ii) {
        const int r = seg * 32 + ii * 2;
        const unsigned int lo = f2bf(ls[r * 132 + cc]);
        const unsigned int hi = f2bf(ls[(r + 1) * 132 + cc]);
        d32[ii] = lo | (hi << 16);
    }
}

// ---------------------------------------------------------------------------
// Kernel 1 (MFMA): patchify + patch embed + pos add -> h0 bf16
// Wave = one image-row of 16 patches (M=16, K=64, N=128):
//   A-frags: lane (m,g) reads 32 B of pixel row (gy*8 + kt*4 + g), cols m*8..
//            -- the patch row IS the MFMA K-layout; fully coalesced, no LDS.
//   B-frags: WpT (bf16, 16 KB, L2-resident).
// ---------------------------------------------------------------------------
__global__ __launch_bounds__(256) void patch_embed_mfma(
    const float* __restrict__ x,       // (B,1,128,128)
    const unsigned short* __restrict__ WpT, // (128,64) bf16
    const float* __restrict__ pb,      // (256,128) = pos + bp
    unsigned short* __restrict__ h0)   // (B,256,128) bf16
{
    const int t = threadIdx.x, w = t >> 6, lane = t & 63;
    const int m = lane & 15, g = lane >> 4;
    const int bi = blockIdx.x;
    const int b  = bi >> 2;
    const int gy = (bi & 3) * 4 + w;

    // A fragments (2 x K=32)
    s16x8 a[2];
#pragma unroll
    for (int kt = 0; kt < 2; ++kt) {
        const float* src = x + ((size_t)b * IMG + gy * PS + kt * 4 + g) * IMG + m * PS;
        const float4 p0 = *(const float4*)src;
        const float4 p1 = *(const float4*)(src + 4);
        s16x8 v;
        v[0] = (short)f2bf(p0.x); v[1] = (short)f2bf(p0.y);
        v[2] = (short)f2bf(p0.z); v[3] = (short)f2bf(p0.w);
        v[4] = (short)f2bf(p1.x); v[5] = (short)f2bf(p1.y);
        v[6] = (short)f2bf(p1.z); v[7] = (short)f2bf(p1.w);
        a[kt] = v;
    }

    f32x4 acc[8];
#pragma unroll
    for (int ct = 0; ct < 8; ++ct) acc[ct] = (f32x4){0.f, 0.f, 0.f, 0.f};

#pragma unroll
    for (int ct = 0; ct < 8; ++ct) {
#pragma unroll
        for (int kt = 0; kt < 2; ++kt) {
            const s16x8 bfr = *(const s16x8*)(WpT + (size_t)(ct * 16 + m) * 64 + kt * 32 + g * 8);
            acc[ct] = __builtin_amdgcn_mfma_f32_16x16x32_bf16(a[kt], bfr, acc[ct], 0, 0, 0);
        }
    }

    // epilogue: row gx = g*4+j, col c = ct*16+m
#pragma unroll
    for (int ct = 0; ct < 8; ++ct)
#pragma unroll
        for (int j = 0; j < 4; ++j) {
            const int p = gy * GRID_P + g * 4 + j;
            const int c = ct * 16 + m;
            const float v = acc[ct][j] + pb[(size_t)p * C + c];
            h0[((size_t)b * NP + p) * C + c] = f2bf(v);
        }
}

// ---------------------------------------------------------------------------
// Kernel 2 (MFMA): quad-group + CP contraction, bf16 in/out.
// Block = 1 wave = (node n, tile of 16 batches):
//   u-phase: 4 GEMMs (16b x 128c)@(128c x 64r), A direct from global h,
//            B direct from global fT; p = elementwise prod of u-accs (regs);
//   LDS roundtrip p -> A-frags (wave-private, no barrier); o-phase GEMM.
// ---------------------------------------------------------------------------
template<int NN, int GIN>
__global__ __launch_bounds__(64) void cp_level_mfma(
    const unsigned short* __restrict__ hin,  // (B, GIN*GIN, C) bf16
    const unsigned short* __restrict__ fT,   // (NN, 4, R, C) bf16
    const unsigned short* __restrict__ oT,   // (NN, C, R) bf16
    unsigned short* __restrict__ hout)       // (B, NN, C) bf16
{
    constexpr int NIN = GIN * GIN;
    constexpr int G2  = GIN / 2;
    constexpr int PSTR = 72;                 // p row stride (2-byte el), 144 B

    __shared__ unsigned short ps[16 * PSTR];

    const int n     = blockIdx.x % NN;
    const int btile = blockIdx.x / NN;
    const int lane = threadIdx.x & 63;
    const int m = lane & 15, g = lane >> 4;
    const int bt = btile * 16;
    const int y1 = n / G2, x1 = n % G2;

    f32x4 acc_u[4][4];
#pragma unroll
    for (int q = 0; q < 4; ++q)
#pragma unroll
        for (int nt = 0; nt < 4; ++nt) acc_u[q][nt] = (f32x4){0.f, 0.f, 0.f, 0.f};

    const unsigned short* fTn = fT + (size_t)n * 4 * R * C;

#pragma unroll
    for (int q = 0; q < 4; ++q) {
        const int pidx = (2 * y1 + (q >> 1)) * GIN + 2 * x1 + (q & 1);
        const unsigned short* xq = hin + ((size_t)(bt + m) * NIN + pidx) * C;
        const unsigned short* fq = fTn + (size_t)q * R * C;
#pragma unroll
        for (int kt = 0; kt < 4; ++kt) {
            const int koff = kt * 32 + g * 8;
            const s16x8 a = *(const s16x8*)(xq + koff);
#pragma unroll
            for (int nt = 0; nt < 4; ++nt) {
                const s16x8 b = *(const s16x8*)(fq + (size_t)(nt * 16 + m) * C + koff);
                acc_u[q][nt] = __builtin_amdgcn_mfma_f32_16x16x32_bf16(a, b, acc_u[q][nt], 0, 0, 0);
            }
        }
    }

    // p-phase: elementwise product across q (identical C-layout)
    f32x4 p[4];
#pragma unroll
    for (int nt = 0; nt < 4; ++nt)
        p[nt] = acc_u[0][nt] * acc_u[1][nt] * acc_u[2][nt] * acc_u[3][nt];

    // stage p to LDS as bf16, rows = local b (0..15), cols = r (0..63)
#pragma unroll
    for (int nt = 0; nt < 4; ++nt)
#pragma unroll
        for (int j = 0; j < 4; ++j)
            ps[(g * 4 + j) * PSTR + nt * 16 + m] = f2bf(p[nt][j]);

    // o-phase
    f32x4 acc_o[8];
#pragma unroll
    for (int ct = 0; ct < 8; ++ct) acc_o[ct] = (f32x4){0.f, 0.f, 0.f, 0.f};

    const unsigned short* oTn = oT + (size_t)n * C * R;
#pragma unroll
    for (int kt = 0; kt < 2; ++kt) {
        const int koff = kt * 32 + g * 8;
        const s16x8 a = *(const s16x8*)(ps + m * PSTR + koff);
#pragma unroll
        for (int ct = 0; ct < 8; ++ct) {
            const s16x8 b = *(const s16x8*)(oTn + (size_t)(ct * 16 + m) * R + koff);
            acc_o[ct] = __builtin_amdgcn_mfma_f32_16x16x32_bf16(a, b, acc_o[ct], 0, 0, 0);
        }
    }

    // store: row b = bt + g*4 + j, col c = ct*16 + m
#pragma unroll
    for (int ct = 0; ct < 8; ++ct)
#pragma unroll
        for (int j = 0; j < 4; ++j) {
            const int row = bt + g * 4 + j;
            hout[((size_t)row * NN + n) * C + ct * 16 + m] = f2bf(acc_o[ct][j]);
        }
}

// ---------------------------------------------------------------------------
// Kernel 3: LayerNorm + head GEMV + L2 normalize (h4 bf16 -> out fp32)
// ---------------------------------------------------------------------------
__global__ __launch_bounds__(256) void head_kernel(
    const unsigned short* __restrict__ h,   // (B, 1, 128) bf16
    const float* __restrict__ gamma, const float* __restrict__ beta,
    const float* __restrict__ Wh,    // (128, 512)
    const float* __restrict__ bh,    // (512)
    float* __restrict__ out)         // (B, 512)
{
    const int b = blockIdx.x;
    const int t = threadIdx.x;
    const int lane = t & 63, wave = t >> 6;
    __shared__ __align__(16) float hn[C];
    __shared__ float red1[4], red2[4], red3[4];

    float v = 0.f;
    if (t < C) v = bf2f(h[(size_t)b * C + t]);
    float s = v, ss = v * v;
#pragma unroll
    for (int off = 32; off >= 1; off >>= 1) {
        s  += __shfl_down(s, off);
        ss += __shfl_down(ss, off);
    }
    if (lane == 0) { red1[wave] = s; red2[wave] = ss; }
    __syncthreads();
    const float sum   = red1[0] + red1[1] + red1[2] + red1[3];
    const float sumsq = red2[0] + red2[1] + red2[2] + red2[3];
    const float mu   = sum * (1.f / C);
    const float var  = sumsq * (1.f / C) - mu * mu;
    const float rstd = rsqrtf(var + 1e-5f);
    if (t < C) hn[t] = (v - mu) * rstd * gamma[t] + beta[t];
    __syncthreads();

    float acc0 = bh[t], acc1 = bh[t + 256];
    for (int c0 = 0; c0 < C; c0 += 4) {
        const float4 hv = *((const float4*)(hn + c0));
        const float* wgt = Wh + (size_t)c0 * E + t;
        acc0 += hv.x * wgt[0] + hv.y * wgt[E] + hv.z * wgt[2 * E] + hv.w * wgt[3 * E];
        const float* w2 = wgt + 256;
        acc1 += hv.x * w2[0] + hv.y * w2[E] + hv.z * w2[2 * E] + hv.w * w2[3 * E];
    }

    float sq = acc0 * acc0 + acc1 * acc1;
#pragma unroll
    for (int off = 32; off >= 1; off >>= 1) sq += __shfl_down(sq, off);
    if (lane == 0) red3[wave] = sq;
    __syncthreads();
    float nrm = sqrtf(red3[0] + red3[1] + red3[2] + red3[3]);
    nrm = fmaxf(nrm, 1e-12f);
    const float inv = 1.f / nrm;
    out[(size_t)b * E + t]       = acc0 * inv;
    out[(size_t)b * E + t + 256] = acc1 * inv;
}

// ---------------------------------------------------------------------------
extern "C" void kernel_launch(void* const* d_in, const int* in_sizes, int n_in,
                              void* d_out, int out_size, void* d_ws, size_t ws_size,
                              hipStream_t stream) {
    const float* x     = (const float*)d_in[0];
    const float* Wp    = (const float*)d_in[1];
    const float* bp    = (const float*)d_in[2];
    const float* pos   = (const float*)d_in[3];
    const float* gamma = (const float*)d_in[4];
    const float* beta  = (const float*)d_in[5];
    const float* Wh    = (const float*)d_in[6];
    const float* bh    = (const float*)d_in[7];
    const float* f0    = (const float*)d_in[8];
    const float* o0    = (const float*)d_in[9];
    const float* f1    = (const float*)d_in[10];
    const float* o1    = (const float*)d_in[11];
    const float* f2    = (const float*)d_in[12];
    const float* o2    = (const float*)d_in[13];
    const float* f3    = (const float*)d_in[14];
    const float* o3    = (const float*)d_in[15];
    float* out = (float*)d_out;

    // workspace layout (bf16 elements unless noted)
    unsigned short* h0 = (unsigned short*)d_ws;            // 16,777,216
    unsigned short* h1 = h0 + (size_t)16777216;            //  4,194,304
    unsigned short* h2 = h1 + (size_t)4194304;             //  1,048,576
    unsigned short* h3 = h2 + (size_t)1048576;             //    262,144
    unsigned short* h4 = h3 + (size_t)262144;              //     65,536
    unsigned short* fT = h4 + (size_t)65536;               //  2,785,280 (340 slices)
    unsigned short* oT = fT + (size_t)2785280;             //    696,320 (85 slices)
    unsigned short* WpT = oT + (size_t)696320;             //      8,192
    float*          pbf = (float*)(WpT + 8192);            //     32,768 fp32

    unsigned short* fT0 = fT;
    unsigned short* fT1 = fT + (size_t)256 * 8192;
    unsigned short* fT2 = fT + (size_t)320 * 8192;
    unsigned short* fT3 = fT + (size_t)336 * 8192;
    unsigned short* oT0 = oT;
    unsigned short* oT1 = oT + (size_t)64 * 8192;
    unsigned short* oT2 = oT + (size_t)80 * 8192;
    unsigned short* oT3 = oT + (size_t)84 * 8192;

    wpt_pb_kernel<<<33, 256, 0, stream>>>(Wp, bp, pos, WpT, pbf);
    f_transpose_kernel<<<340, 256, 0, stream>>>(f0, f1, f2, f3, fT);
    o_transpose_kernel<<< 85, 256, 0, stream>>>(o0, o1, o2, o3, oT);

    patch_embed_mfma<<<BATCH * 4, 256, 0, stream>>>(x, WpT, pbf, h0);

    cp_level_mfma<64, 16><<<64 * 32, 64, 0, stream>>>(h0, fT0, oT0, h1);
    cp_level_mfma<16,  8><<<16 * 32, 64, 0, stream>>>(h1, fT1, oT1, h2);
    cp_level_mfma< 4,  4><<< 4 * 32, 64, 0, stream>>>(h2, fT2, oT2, h3);
    cp_level_mfma< 1,  2><<< 1 * 32, 64, 0, stream>>>(h3, fT3, oT3, h4);

    head_kernel<<<BATCH, 256, 0, stream>>>(h4, gamma, beta, Wh, bh, out);
}

// Round 5
// 173.294 us; speedup vs baseline: 2.1729x; 1.1146x over previous
//
#include <hip/hip_runtime.h>
#include <hip/hip_bf16.h>

// Problem constants
#define BATCH     512
#define IMG       128
#define PS        8
#define GRID_P    16      // IMG/PS
#define NP        256     // GRID_P*GRID_P
#define C         128     // BOND_DIM
#define R         64      // CP_RANK
#define E         512     // EMBED_DIM

typedef float f32x4 __attribute__((ext_vector_type(4)));
typedef short s16x8 __attribute__((ext_vector_type(8)));

__device__ __forceinline__ unsigned short f2bf(float x) {
    unsigned int u = __float_as_uint(x);
    u += 0x7fffu + ((u >> 16) & 1u);          // RNE
    return (unsigned short)(u >> 16);
}
__device__ __forceinline__ float bf2f(unsigned short h) {
    return __uint_as_float(((unsigned int)h) << 16);
}

// ---------------------------------------------------------------------------
// Wp fp32 (64x128) -> bf16 native layout (B^T[k][c], c contiguous)
// ---------------------------------------------------------------------------
__global__ __launch_bounds__(256) void wp_conv_kernel(
    const float* __restrict__ Wp, unsigned short* __restrict__ Wp_bf)
{
    const int t = threadIdx.x;
#pragma unroll
    for (int i = 0; i < 32; ++i) {
        const int idx = i * 256 + t;
        Wp_bf[idx] = f2bf(Wp[idx]);
    }
}

// ---------------------------------------------------------------------------
// Transpose+convert f (levels 0..3): slices of (C=128 x R=64) fp32 ->
// fT slices (R=64 x C=128) bf16. 340 slices total, contiguous in fT.
// ---------------------------------------------------------------------------
__global__ __launch_bounds__(256) void f_transpose_kernel(
    const float* __restrict__ f0, const float* __restrict__ f1,
    const float* __restrict__ f2, const float* __restrict__ f3,
    unsigned short* __restrict__ fT)
{
    __shared__ float ls[128 * 68];
    const int bi = blockIdx.x, t = threadIdx.x;
    const float* src;
    if      (bi < 256) src = f0 + (size_t)bi * 8192;
    else if (bi < 320) src = f1 + (size_t)(bi - 256) * 8192;
    else if (bi < 336) src = f2 + (size_t)(bi - 320) * 8192;
    else               src = f3 + (size_t)(bi - 336) * 8192;
    unsigned short* dst = fT + (size_t)bi * 8192;

#pragma unroll
    for (int i = 0; i < 8; ++i) {
        const int fi = (t + 256 * i) * 4;
        const int c = fi >> 6, r = fi & 63;          // in[c][r]
        *(float4*)(ls + c * 68 + r) = *(const float4*)(src + fi);
    }
    __syncthreads();
    const int rr = t >> 2, seg = t & 3;              // out row rr (r), 4 thr/row
    unsigned int* d32 = (unsigned int*)(dst + rr * 128 + seg * 32);
#pragma unroll
    for (int ii = 0; ii < 16; ++ii) {
        const int c = seg * 32 + ii * 2;
        const unsigned int lo = f2bf(ls[c * 68 + rr]);
        const unsigned int hi = f2bf(ls[(c + 1) * 68 + rr]);
        d32[ii] = lo | (hi << 16);
    }
}

// ---------------------------------------------------------------------------
// Transpose+convert o (levels 0..3): slices (R=64 x C=128) fp32 ->
// oT slices (C=128 x R=64) bf16. 85 slices total.
// ---------------------------------------------------------------------------
__global__ __launch_bounds__(256) void o_transpose_kernel(
    const float* __restrict__ o0, const float* __restrict__ o1,
    const float* __restrict__ o2, const float* __restrict__ o3,
    unsigned short* __restrict__ oT)
{
    __shared__ float ls[64 * 132];
    const int bi = blockIdx.x, t = threadIdx.x;
    const float* src;
    if      (bi < 64) src = o0 + (size_t)bi * 8192;
    else if (bi < 80) src = o1 + (size_t)(bi - 64) * 8192;
    else if (bi < 84) src = o2 + (size_t)(bi - 80) * 8192;
    else              src = o3 + (size_t)(bi - 84) * 8192;
    unsigned short* dst = oT + (size_t)bi * 8192;

#pragma unroll
    for (int i = 0; i < 8; ++i) {
        const int fi = (t + 256 * i) * 4;
        const int r = fi >> 7, c = fi & 127;         // in[r][c]
        *(float4*)(ls + r * 132 + c) = *(const float4*)(src + fi);
    }
    __syncthreads();
    const int cc = t >> 1, seg = t & 1;              // out row cc (c), 2 thr/row
    unsigned int* d32 = (unsigned int*)(dst + cc * 64 + seg * 32);
#pragma unroll
    for (int ii = 0; ii < 16; ++ii) {
        const int r = seg * 32 + ii * 2;
        const unsigned int lo = f2bf(ls[r * 132 + cc]);
        const unsigned int hi = f2bf(ls[(r + 1) * 132 + cc]);
        d32[ii] = lo | (hi << 16);
    }
}

// ---------------------------------------------------------------------------
// WfT[n,q][r][k] = sum_c Wp[k][c] * f0[n,q][c][r]   (64x64 bf16, k contiguous)
// computed as (fT0 slice 64r x 128c) @ Wp_bf^T via MFMA. 1 wave per (n,q).
// ---------------------------------------------------------------------------
__global__ __launch_bounds__(64) void wft_mfma_kernel(
    const unsigned short* __restrict__ fT0,    // 256 slices (64 x 128)
    const unsigned short* __restrict__ Wp_bf,  // (64 x 128), B^T layout
    unsigned short* __restrict__ WfT)          // 256 slices (64 x 64)
{
    const int blk  = blockIdx.x;               // n*4+q
    const int lane = threadIdx.x & 63;
    const int m = lane & 15, g = lane >> 4;
    const unsigned short* A = fT0 + (size_t)blk * 8192;

    f32x4 acc[4][4];
#pragma unroll
    for (int mt = 0; mt < 4; ++mt)
#pragma unroll
        for (int nt = 0; nt < 4; ++nt) acc[mt][nt] = (f32x4){0.f, 0.f, 0.f, 0.f};

#pragma unroll
    for (int kt = 0; kt < 4; ++kt) {
        const int koff = kt * 32 + g * 8;
        s16x8 afr[4], bfr[4];
#pragma unroll
        for (int mt = 0; mt < 4; ++mt)
            afr[mt] = *(const s16x8*)(A + (size_t)(mt * 16 + m) * 128 + koff);
#pragma unroll
        for (int nt = 0; nt < 4; ++nt)
            bfr[nt] = *(const s16x8*)(Wp_bf + (size_t)(nt * 16 + m) * 128 + koff);
#pragma unroll
        for (int mt = 0; mt < 4; ++mt)
#pragma unroll
            for (int nt = 0; nt < 4; ++nt)
                acc[mt][nt] = __builtin_amdgcn_mfma_f32_16x16x32_bf16(afr[mt], bfr[nt], acc[mt][nt], 0, 0, 0);
    }

    unsigned short* D = WfT + (size_t)blk * 4096;
#pragma unroll
    for (int mt = 0; mt < 4; ++mt)
#pragma unroll
        for (int nt = 0; nt < 4; ++nt)
#pragma unroll
            for (int j = 0; j < 4; ++j)
                D[(size_t)(mt * 16 + g * 4 + j) * 64 + nt * 16 + m] = f2bf(acc[mt][nt][j]);
}

// ---------------------------------------------------------------------------
// pf[n,q][r] = sum_c (pos[p][c] + bp[c]) * f0[n,q][c][r], fp32 (C-initializer)
// ---------------------------------------------------------------------------
__global__ __launch_bounds__(64) void pf_kernel(
    const unsigned short* __restrict__ fT0, const float* __restrict__ pos,
    const float* __restrict__ bp, float* __restrict__ pf)
{
    const int blk = blockIdx.x;                // n*4+q
    const int n = blk >> 2, q = blk & 3;
    const int r = threadIdx.x & 63;
    const int p = (2 * (n >> 3) + (q >> 1)) * GRID_P + 2 * (n & 7) + (q & 1);
    const unsigned short* frow = fT0 + (size_t)blk * 8192 + (size_t)r * 128;
    const float* pp = pos + (size_t)p * C;
    float s = 0.f;
#pragma unroll 4
    for (int c = 0; c < C; ++c) s += (pp[c] + bp[c]) * bf2f(frow[c]);
    pf[blk * 64 + r] = s;
}

// ---------------------------------------------------------------------------
// Level 0 FUSED: pixels -> u (via precomputed WfT, pf) -> p -> o -> h1.
// Wave = (node n, 16 batches). A-frags read raw pixels (patch row = K-layout).
//   u[b,r] = sum_k pix[b, pidx, k] * WfT[r][k] + pf[r]   (K=64, 2 MFMA steps)
// Grid n-major (bi = n*32 + btile) for L2 locality on WfT/oT.
// ---------------------------------------------------------------------------
__global__ __launch_bounds__(64) void cp_level0_fused(
    const float* __restrict__ x,              // (B,1,128,128)
    const unsigned short* __restrict__ WfT,   // (64,4,64,64) bf16
    const float* __restrict__ pf,             // (64,4,64) fp32
    const unsigned short* __restrict__ oT0,   // (64,128,64) bf16
    unsigned short* __restrict__ h1)          // (B,64,128) bf16
{
    constexpr int NN = 64;
    constexpr int PSTR = 72;
    __shared__ unsigned short ps[16 * PSTR];

    const int bi = blockIdx.x;
    const int n = bi >> 5, btile = bi & 31;
    const int lane = threadIdx.x & 63;
    const int m = lane & 15, g = lane >> 4;
    const int bt = btile * 16;
    const int y1 = n >> 3, x1 = n & 7;
    const int b = bt + m;

    // pixel A-fragments: a[q][kt] = pix rows of patch q, k = kt*32+g*8..+8
    s16x8 a[4][2];
#pragma unroll
    for (int q = 0; q < 4; ++q) {
        const int py = (2 * y1 + (q >> 1)) * PS;
        const int px = (2 * x1 + (q & 1)) * PS;
#pragma unroll
        for (int kt = 0; kt < 2; ++kt) {
            const float* src = x + ((size_t)b * IMG + py + kt * 4 + g) * IMG + px;
            const float4 p0 = *(const float4*)src;
            const float4 p1 = *(const float4*)(src + 4);
            s16x8 v;
            v[0] = (short)f2bf(p0.x); v[1] = (short)f2bf(p0.y);
            v[2] = (short)f2bf(p0.z); v[3] = (short)f2bf(p0.w);
            v[4] = (short)f2bf(p1.x); v[5] = (short)f2bf(p1.y);
            v[6] = (short)f2bf(p1.z); v[7] = (short)f2bf(p1.w);
            a[q][kt] = v;
        }
    }

    // u-phase, C initialized with pf
    f32x4 acc_u[4][4];
#pragma unroll
    for (int q = 0; q < 4; ++q) {
        const float* pfq = pf + (size_t)(n * 4 + q) * 64;
#pragma unroll
        for (int nt = 0; nt < 4; ++nt) {
            const float pv = pfq[nt * 16 + m];
            acc_u[q][nt] = (f32x4){pv, pv, pv, pv};
        }
    }
#pragma unroll
    for (int q = 0; q < 4; ++q) {
        const unsigned short* Wq = WfT + (size_t)(n * 4 + q) * 4096;
#pragma unroll
        for (int kt = 0; kt < 2; ++kt) {
            const int koff = kt * 32 + g * 8;
#pragma unroll
            for (int nt = 0; nt < 4; ++nt) {
                const s16x8 bfr = *(const s16x8*)(Wq + (size_t)(nt * 16 + m) * 64 + koff);
                acc_u[q][nt] = __builtin_amdgcn_mfma_f32_16x16x32_bf16(a[q][kt], bfr, acc_u[q][nt], 0, 0, 0);
            }
        }
    }

    // p-phase
    f32x4 p[4];
#pragma unroll
    for (int nt = 0; nt < 4; ++nt)
        p[nt] = acc_u[0][nt] * acc_u[1][nt] * acc_u[2][nt] * acc_u[3][nt];

#pragma unroll
    for (int nt = 0; nt < 4; ++nt)
#pragma unroll
        for (int j = 0; j < 4; ++j)
            ps[(g * 4 + j) * PSTR + nt * 16 + m] = f2bf(p[nt][j]);

    // o-phase
    f32x4 acc_o[8];
#pragma unroll
    for (int ct = 0; ct < 8; ++ct) acc_o[ct] = (f32x4){0.f, 0.f, 0.f, 0.f};

    const unsigned short* oTn = oT0 + (size_t)n * C * R;
#pragma unroll
    for (int kt = 0; kt < 2; ++kt) {
        const int koff = kt * 32 + g * 8;
        const s16x8 afr = *(const s16x8*)(ps + m * PSTR + koff);
#pragma unroll
        for (int ct = 0; ct < 8; ++ct) {
            const s16x8 bfr = *(const s16x8*)(oTn + (size_t)(ct * 16 + m) * R + koff);
            acc_o[ct] = __builtin_amdgcn_mfma_f32_16x16x32_bf16(afr, bfr, acc_o[ct], 0, 0, 0);
        }
    }

#pragma unroll
    for (int ct = 0; ct < 8; ++ct)
#pragma unroll
        for (int j = 0; j < 4; ++j) {
            const int row = bt + g * 4 + j;
            h1[((size_t)row * NN + n) * C + ct * 16 + m] = f2bf(acc_o[ct][j]);
        }
}

// ---------------------------------------------------------------------------
// Levels 1-3 (MFMA): quad-group + CP contraction, bf16 in/out. 1 wave/block.
// ---------------------------------------------------------------------------
template<int NN, int GIN>
__global__ __launch_bounds__(64) void cp_level_mfma(
    const unsigned short* __restrict__ hin,  // (B, GIN*GIN, C) bf16
    const unsigned short* __restrict__ fT,   // (NN, 4, R, C) bf16
    const unsigned short* __restrict__ oT,   // (NN, C, R) bf16
    unsigned short* __restrict__ hout)       // (B, NN, C) bf16
{
    constexpr int NIN = GIN * GIN;
    constexpr int G2  = GIN / 2;
    constexpr int PSTR = 72;

    __shared__ unsigned short ps[16 * PSTR];

    const int n     = blockIdx.x % NN;
    const int btile = blockIdx.x / NN;
    const int lane = threadIdx.x & 63;
    const int m = lane & 15, g = lane >> 4;
    const int bt = btile * 16;
    const int y1 = n / G2, x1 = n % G2;

    f32x4 acc_u[4][4];
#pragma unroll
    for (int q = 0; q < 4; ++q)
#pragma unroll
        for (int nt = 0; nt < 4; ++nt) acc_u[q][nt] = (f32x4){0.f, 0.f, 0.f, 0.f};

    const unsigned short* fTn = fT + (size_t)n * 4 * R * C;

#pragma unroll
    for (int q = 0; q < 4; ++q) {
        const int pidx = (2 * y1 + (q >> 1)) * GIN + 2 * x1 + (q & 1);
        const unsigned short* xq = hin + ((size_t)(bt + m) * NIN + pidx) * C;
        const unsigned short* fq = fTn + (size_t)q * R * C;
#pragma unroll
        for (int kt = 0; kt < 4; ++kt) {
            const int koff = kt * 32 + g * 8;
            const s16x8 a = *(const s16x8*)(xq + koff);
#pragma unroll
            for (int nt = 0; nt < 4; ++nt) {
                const s16x8 b = *(const s16x8*)(fq + (size_t)(nt * 16 + m) * C + koff);
                acc_u[q][nt] = __builtin_amdgcn_mfma_f32_16x16x32_bf16(a, b, acc_u[q][nt], 0, 0, 0);
            }
        }
    }

    f32x4 p[4];
#pragma unroll
    for (int nt = 0; nt < 4; ++nt)
        p[nt] = acc_u[0][nt] * acc_u[1][nt] * acc_u[2][nt] * acc_u[3][nt];

#pragma unroll
    for (int nt = 0; nt < 4; ++nt)
#pragma unroll
        for (int j = 0; j < 4; ++j)
            ps[(g * 4 + j) * PSTR + nt * 16 + m] = f2bf(p[nt][j]);

    f32x4 acc_o[8];
#pragma unroll
    for (int ct = 0; ct < 8; ++ct) acc_o[ct] = (f32x4){0.f, 0.f, 0.f, 0.f};

    const unsigned short* oTn = oT + (size_t)n * C * R;
#pragma unroll
    for (int kt = 0; kt < 2; ++kt) {
        const int koff = kt * 32 + g * 8;
        const s16x8 a = *(const s16x8*)(ps + m * PSTR + koff);
#pragma unroll
        for (int ct = 0; ct < 8; ++ct) {
            const s16x8 b = *(const s16x8*)(oTn + (size_t)(ct * 16 + m) * R + koff);
            acc_o[ct] = __builtin_amdgcn_mfma_f32_16x16x32_bf16(a, b, acc_o[ct], 0, 0, 0);
        }
    }

#pragma unroll
    for (int ct = 0; ct < 8; ++ct)
#pragma unroll
        for (int j = 0; j < 4; ++j) {
            const int row = bt + g * 4 + j;
            hout[((size_t)row * NN + n) * C + ct * 16 + m] = f2bf(acc_o[ct][j]);
        }
}

// ---------------------------------------------------------------------------
// Kernel 3: LayerNorm + head GEMV + L2 normalize (h4 bf16 -> out fp32)
// ---------------------------------------------------------------------------
__global__ __launch_bounds__(256) void head_kernel(
    const unsigned short* __restrict__ h,   // (B, 1, 128) bf16
    const float* __restrict__ gamma, const float* __restrict__ beta,
    const float* __restrict__ Wh,    // (128, 512)
    const float* __restrict__ bh,    // (512)
    float* __restrict__ out)         // (B, 512)
{
    const int b = blockIdx.x;
    const int t = threadIdx.x;
    const int lane = t & 63, wave = t >> 6;
    __shared__ __align__(16) float hn[C];
    __shared__ float red1[4], red2[4], red3[4];

    float v = 0.f;
    if (t < C) v = bf2f(h[(size_t)b * C + t]);
    float s = v, ss = v * v;
#pragma unroll
    for (int off = 32; off >= 1; off >>= 1) {
        s  += __shfl_down(s, off);
        ss += __shfl_down(ss, off);
    }
    if (lane == 0) { red1[wave] = s; red2[wave] = ss; }
    __syncthreads();
    const float sum   = red1[0] + red1[1] + red1[2] + red1[3];
    const float sumsq = red2[0] + red2[1] + red2[2] + red2[3];
    const float mu   = sum * (1.f / C);
    const float var  = sumsq * (1.f / C) - mu * mu;
    const float rstd = rsqrtf(var + 1e-5f);
    if (t < C) hn[t] = (v - mu) * rstd * gamma[t] + beta[t];
    __syncthreads();

    float acc0 = bh[t], acc1 = bh[t + 256];
    for (int c0 = 0; c0 < C; c0 += 4) {
        const float4 hv = *((const float4*)(hn + c0));
        const float* wgt = Wh + (size_t)c0 * E + t;
        acc0 += hv.x * wgt[0] + hv.y * wgt[E] + hv.z * wgt[2 * E] + hv.w * wgt[3 * E];
        const float* w2 = wgt + 256;
        acc1 += hv.x * w2[0] + hv.y * w2[E] + hv.z * w2[2 * E] + hv.w * w2[3 * E];
    }

    float sq = acc0 * acc0 + acc1 * acc1;
#pragma unroll
    for (int off = 32; off >= 1; off >>= 1) sq += __shfl_down(sq, off);
    if (lane == 0) red3[wave] = sq;
    __syncthreads();
    float nrm = sqrtf(red3[0] + red3[1] + red3[2] + red3[3]);
    nrm = fmaxf(nrm, 1e-12f);
    const float inv = 1.f / nrm;
    out[(size_t)b * E + t]       = acc0 * inv;
    out[(size_t)b * E + t + 256] = acc1 * inv;
}

// ---------------------------------------------------------------------------
extern "C" void kernel_launch(void* const* d_in, const int* in_sizes, int n_in,
                              void* d_out, int out_size, void* d_ws, size_t ws_size,
                              hipStream_t stream) {
    const float* x     = (const float*)d_in[0];
    const float* Wp    = (const float*)d_in[1];
    const float* bp    = (const float*)d_in[2];
    const float* pos   = (const float*)d_in[3];
    const float* gamma = (const float*)d_in[4];
    const float* beta  = (const float*)d_in[5];
    const float* Wh    = (const float*)d_in[6];
    const float* bh    = (const float*)d_in[7];
    const float* f0    = (const float*)d_in[8];
    const float* o0    = (const float*)d_in[9];
    const float* f1    = (const float*)d_in[10];
    const float* o1    = (const float*)d_in[11];
    const float* f2    = (const float*)d_in[12];
    const float* o2    = (const float*)d_in[13];
    const float* f3    = (const float*)d_in[14];
    const float* o3    = (const float*)d_in[15];
    float* out = (float*)d_out;

    // workspace layout (bf16 elements unless noted)
    unsigned short* h1  = (unsigned short*)d_ws;           //  4,194,304
    unsigned short* h2  = h1 + (size_t)4194304;            //  1,048,576
    unsigned short* h3  = h2 + (size_t)1048576;            //    262,144
    unsigned short* h4  = h3 + (size_t)262144;             //     65,536
    unsigned short* fT  = h4 + (size_t)65536;              //  2,785,280 (340 slices)
    unsigned short* oT  = fT + (size_t)2785280;            //    696,320 (85 slices)
    unsigned short* Wpb = oT + (size_t)696320;             //      8,192
    unsigned short* WfT = Wpb + (size_t)8192;              //  1,048,576 (256 x 64x64)
    float*          pff = (float*)(WfT + 1048576);         //     16,384 fp32

    unsigned short* fT0 = fT;
    unsigned short* fT1 = fT + (size_t)256 * 8192;
    unsigned short* fT2 = fT + (size_t)320 * 8192;
    unsigned short* fT3 = fT + (size_t)336 * 8192;
    unsigned short* oT0 = oT;
    unsigned short* oT1 = oT + (size_t)64 * 8192;
    unsigned short* oT2 = oT + (size_t)80 * 8192;
    unsigned short* oT3 = oT + (size_t)84 * 8192;

    wp_conv_kernel<<<1, 256, 0, stream>>>(Wp, Wpb);
    f_transpose_kernel<<<340, 256, 0, stream>>>(f0, f1, f2, f3, fT);
    o_transpose_kernel<<< 85, 256, 0, stream>>>(o0, o1, o2, o3, oT);
    wft_mfma_kernel<<<256, 64, 0, stream>>>(fT0, Wpb, WfT);
    pf_kernel<<<256, 64, 0, stream>>>(fT0, pos, bp, pff);

    cp_level0_fused<<<64 * 32, 64, 0, stream>>>(x, WfT, pff, oT0, h1);

    cp_level_mfma<16,  8><<<16 * 32, 64, 0, stream>>>(h1, fT1, oT1, h2);
    cp_level_mfma< 4,  4><<< 4 * 32, 64, 0, stream>>>(h2, fT2, oT2, h3);
    cp_level_mfma< 1,  2><<< 1 * 32, 64, 0, stream>>>(h3, fT3, oT3, h4);

    head_kernel<<<BATCH, 256, 0, stream>>>(h4, gamma, beta, Wh, bh, out);
}

// Round 6
// 165.525 us; speedup vs baseline: 2.2749x; 1.0469x over previous
//
#include <hip/hip_runtime.h>
#include <hip/hip_bf16.h>

// Problem constants
#define BATCH     512
#define IMG       128
#define PS        8
#define GRID_P    16      // IMG/PS
#define NP        256     // GRID_P*GRID_P
#define C         128     // BOND_DIM
#define R         64      // CP_RANK
#define E         512     // EMBED_DIM

typedef float f32x4 __attribute__((ext_vector_type(4)));
typedef short s16x8 __attribute__((ext_vector_type(8)));

__device__ __forceinline__ unsigned short f2bf(float x) {
    unsigned int u = __float_as_uint(x);
    u += 0x7fffu + ((u >> 16) & 1u);          // RNE
    return (unsigned short)(u >> 16);
}
__device__ __forceinline__ float bf2f(unsigned short h) {
    return __uint_as_float(((unsigned int)h) << 16);
}

// ---------------------------------------------------------------------------
// Prep kernel (one launch):
//   bi <340        : f slices (128c x 64r) fp32 -> fT (64r x 128c) bf16
//   bi 340..424    : o slices (64r x 128c) fp32 -> oT (128c x 64r) bf16
//   bi 425..432    : Wh (128c x 512e) fp32 -> WhT (512e x 128c) bf16, 64 e/blk
//   bi 433         : Wp fp32 -> bf16 (native layout)
// ---------------------------------------------------------------------------
__global__ __launch_bounds__(256) void prep_kernel(
    const float* __restrict__ f0, const float* __restrict__ f1,
    const float* __restrict__ f2, const float* __restrict__ f3,
    const float* __restrict__ o0, const float* __restrict__ o1,
    const float* __restrict__ o2, const float* __restrict__ o3,
    const float* __restrict__ Wh, const float* __restrict__ Wp,
    unsigned short* __restrict__ fT, unsigned short* __restrict__ oT,
    unsigned short* __restrict__ WhT, unsigned short* __restrict__ Wp_bf)
{
    __shared__ float ls[128 * 68];
    const int bi = blockIdx.x, t = threadIdx.x;

    if (bi < 340) {
        const float* src;
        if      (bi < 256) src = f0 + (size_t)bi * 8192;
        else if (bi < 320) src = f1 + (size_t)(bi - 256) * 8192;
        else if (bi < 336) src = f2 + (size_t)(bi - 320) * 8192;
        else               src = f3 + (size_t)(bi - 336) * 8192;
        unsigned short* dst = fT + (size_t)bi * 8192;
#pragma unroll
        for (int i = 0; i < 8; ++i) {
            const int fi = (t + 256 * i) * 4;
            const int c = fi >> 6, r = fi & 63;          // in[c][r]
            *(float4*)(ls + c * 68 + r) = *(const float4*)(src + fi);
        }
        __syncthreads();
        const int rr = t >> 2, seg = t & 3;
        unsigned int* d32 = (unsigned int*)(dst + rr * 128 + seg * 32);
#pragma unroll
        for (int ii = 0; ii < 16; ++ii) {
            const int c = seg * 32 + ii * 2;
            const unsigned int lo = f2bf(ls[c * 68 + rr]);
            const unsigned int hi = f2bf(ls[(c + 1) * 68 + rr]);
            d32[ii] = lo | (hi << 16);
        }
    } else if (bi < 425) {
        const int oi = bi - 340;
        const float* src;
        if      (oi < 64) src = o0 + (size_t)oi * 8192;
        else if (oi < 80) src = o1 + (size_t)(oi - 64) * 8192;
        else if (oi < 84) src = o2 + (size_t)(oi - 80) * 8192;
        else              src = o3 + (size_t)(oi - 84) * 8192;
        unsigned short* dst = oT + (size_t)oi * 8192;
        // in (64r x 128c) -> ls[r][c] with stride 132 (fits in 128*68 buffer)
#pragma unroll
        for (int i = 0; i < 8; ++i) {
            const int fi = (t + 256 * i) * 4;
            const int r = fi >> 7, c = fi & 127;
            *(float4*)(ls + r * 132 + c) = *(const float4*)(src + fi);
        }
        __syncthreads();
        const int cc = t >> 1, seg = t & 1;
        unsigned int* d32 = (unsigned int*)(dst + cc * 64 + seg * 32);
#pragma unroll
        for (int ii = 0; ii < 16; ++ii) {
            const int r = seg * 32 + ii * 2;
            const unsigned int lo = f2bf(ls[r * 132 + cc]);
            const unsigned int hi = f2bf(ls[(r + 1) * 132 + cc]);
            d32[ii] = lo | (hi << 16);
        }
    } else if (bi < 433) {
        const int j = bi - 425;                          // e-chunk (64 cols)
        // load Wh[c][j*64 + e] -> ls[c][e] (128 x 64, stride 68)
#pragma unroll
        for (int i = 0; i < 8; ++i) {
            const int fi = (t + 256 * i) * 4;
            const int c = fi >> 6, e = fi & 63;
            *(float4*)(ls + c * 68 + e) = *(const float4*)(Wh + (size_t)c * E + j * 64 + e);
        }
        __syncthreads();
        const int rr = t >> 2, seg = t & 3;              // rr = e_local
        unsigned int* d32 = (unsigned int*)(WhT + (size_t)(j * 64 + rr) * 128 + seg * 32);
#pragma unroll
        for (int ii = 0; ii < 16; ++ii) {
            const int c = seg * 32 + ii * 2;
            const unsigned int lo = f2bf(ls[c * 68 + rr]);
            const unsigned int hi = f2bf(ls[(c + 1) * 68 + rr]);
            d32[ii] = lo | (hi << 16);
        }
    } else {
#pragma unroll
        for (int i = 0; i < 32; ++i) {
            const int idx = i * 256 + t;
            Wp_bf[idx] = f2bf(Wp[idx]);
        }
    }
}

// ---------------------------------------------------------------------------
// WfT[n,q][r][k] = sum_c Wp[k][c] * f0[n,q][c][r] (bi<256, MFMA)
// pf[n,q][r]    = sum_c (pos[p][c]+bp[c]) * f0[n,q][c][r] (bi>=256)
// ---------------------------------------------------------------------------
__global__ __launch_bounds__(64) void wft_pf_kernel(
    const unsigned short* __restrict__ fT0,    // 256 slices (64 x 128)
    const unsigned short* __restrict__ Wp_bf,  // (64 x 128)
    const float* __restrict__ pos, const float* __restrict__ bp,
    unsigned short* __restrict__ WfT,          // 256 slices (64 x 64)
    float* __restrict__ pf)                    // (256 x 64)
{
    const int bi = blockIdx.x;
    if (bi < 256) {
        const int blk  = bi;
        const int lane = threadIdx.x & 63;
        const int m = lane & 15, g = lane >> 4;
        const unsigned short* A = fT0 + (size_t)blk * 8192;

        f32x4 acc[4][4];
#pragma unroll
        for (int mt = 0; mt < 4; ++mt)
#pragma unroll
            for (int nt = 0; nt < 4; ++nt) acc[mt][nt] = (f32x4){0.f, 0.f, 0.f, 0.f};

#pragma unroll
        for (int kt = 0; kt < 4; ++kt) {
            const int koff = kt * 32 + g * 8;
            s16x8 afr[4], bfr[4];
#pragma unroll
            for (int mt = 0; mt < 4; ++mt)
                afr[mt] = *(const s16x8*)(A + (size_t)(mt * 16 + m) * 128 + koff);
#pragma unroll
            for (int nt = 0; nt < 4; ++nt)
                bfr[nt] = *(const s16x8*)(Wp_bf + (size_t)(nt * 16 + m) * 128 + koff);
#pragma unroll
            for (int mt = 0; mt < 4; ++mt)
#pragma unroll
                for (int nt = 0; nt < 4; ++nt)
                    acc[mt][nt] = __builtin_amdgcn_mfma_f32_16x16x32_bf16(afr[mt], bfr[nt], acc[mt][nt], 0, 0, 0);
        }

        unsigned short* D = WfT + (size_t)blk * 4096;
#pragma unroll
        for (int mt = 0; mt < 4; ++mt)
#pragma unroll
            for (int nt = 0; nt < 4; ++nt)
#pragma unroll
                for (int j = 0; j < 4; ++j)
                    D[(size_t)(mt * 16 + g * 4 + j) * 64 + nt * 16 + m] = f2bf(acc[mt][nt][j]);
    } else {
        const int blk = bi - 256;                // n*4+q
        const int n = blk >> 2, q = blk & 3;
        const int r = threadIdx.x & 63;
        const int p = (2 * (n >> 3) + (q >> 1)) * GRID_P + 2 * (n & 7) + (q & 1);
        const unsigned short* frow = fT0 + (size_t)blk * 8192 + (size_t)r * 128;
        const float* pp = pos + (size_t)p * C;
        float s = 0.f;
#pragma unroll 4
        for (int c = 0; c < C; ++c) s += (pp[c] + bp[c]) * bf2f(frow[c]);
        pf[blk * 64 + r] = s;
    }
}

// ---------------------------------------------------------------------------
// Level 0 FUSED, 4 waves/block: wave = quadrant q.
//   u-phase: pixels (patch row = K-layout) @ WfT, +pf init; 8 MFMA/wave.
//   stage u -> LDS fp32 (stride 68), barrier, block p-phase, barrier,
//   o-phase split by ct across waves (4 MFMA/wave).
// Grid = 64 n * 32 btile (n-major), 8 blocks/CU, 32 waves/CU.
// ---------------------------------------------------------------------------
__global__ __launch_bounds__(256) void cp_level0_fused(
    const float* __restrict__ x,              // (B,1,128,128)
    const unsigned short* __restrict__ WfT,   // (64,4,64,64) bf16
    const float* __restrict__ pf,             // (64,4,64) fp32
    const unsigned short* __restrict__ oT0,   // (64,128,64) bf16
    unsigned short* __restrict__ h1)          // (B,64,128) bf16
{
    constexpr int NN = 64;
    __shared__ __align__(16) float us[4 * 16 * 68];       // 17408 B
    __shared__ __align__(16) unsigned short ps[16 * 72];  //  2304 B

    const int bi = blockIdx.x;
    const int n = bi >> 5, btile = bi & 31;
    const int t = threadIdx.x, w = t >> 6, lane = t & 63;
    const int m = lane & 15, g = lane >> 4;
    const int bt = btile * 16;
    const int y1 = n >> 3, x1 = n & 7;
    const int b = bt + m;
    const int q = w;

    // pixel A-fragments for this wave's quadrant
    const int py = (2 * y1 + (q >> 1)) * PS;
    const int px = (2 * x1 + (q & 1)) * PS;
    s16x8 a[2];
#pragma unroll
    for (int kt = 0; kt < 2; ++kt) {
        const float* src = x + ((size_t)b * IMG + py + kt * 4 + g) * IMG + px;
        const float4 p0 = *(const float4*)src;
        const float4 p1 = *(const float4*)(src + 4);
        s16x8 v;
        v[0] = (short)f2bf(p0.x); v[1] = (short)f2bf(p0.y);
        v[2] = (short)f2bf(p0.z); v[3] = (short)f2bf(p0.w);
        v[4] = (short)f2bf(p1.x); v[5] = (short)f2bf(p1.y);
        v[6] = (short)f2bf(p1.z); v[7] = (short)f2bf(p1.w);
        a[kt] = v;
    }

    // u-phase (+pf init)
    const float* pfq = pf + (size_t)(n * 4 + q) * 64;
    f32x4 acc_u[4];
#pragma unroll
    for (int nt = 0; nt < 4; ++nt) {
        const float pv = pfq[nt * 16 + m];
        acc_u[nt] = (f32x4){pv, pv, pv, pv};
    }
    const unsigned short* Wq = WfT + (size_t)(n * 4 + q) * 4096;
#pragma unroll
    for (int kt = 0; kt < 2; ++kt) {
        const int koff = kt * 32 + g * 8;
#pragma unroll
        for (int nt = 0; nt < 4; ++nt) {
            const s16x8 bfr = *(const s16x8*)(Wq + (size_t)(nt * 16 + m) * 64 + koff);
            acc_u[nt] = __builtin_amdgcn_mfma_f32_16x16x32_bf16(a[kt], bfr, acc_u[nt], 0, 0, 0);
        }
    }
    // stage u: row = q*16 + (g*4+j), col = nt*16+m
#pragma unroll
    for (int nt = 0; nt < 4; ++nt)
#pragma unroll
        for (int j = 0; j < 4; ++j)
            us[(q * 16 + g * 4 + j) * 68 + nt * 16 + m] = acc_u[nt][j];
    __syncthreads();

    // p-phase: thread t -> b = t>>4, r0 = (t&15)*4
    {
        const int pb = t >> 4, r0 = (t & 15) * 4;
        const f32x4 u0 = *(const f32x4*)(us + (0 * 16 + pb) * 68 + r0);
        const f32x4 u1 = *(const f32x4*)(us + (1 * 16 + pb) * 68 + r0);
        const f32x4 u2 = *(const f32x4*)(us + (2 * 16 + pb) * 68 + r0);
        const f32x4 u3 = *(const f32x4*)(us + (3 * 16 + pb) * 68 + r0);
        const f32x4 p = u0 * u1 * u2 * u3;
        uint2 v;
        v.x = (unsigned int)f2bf(p[0]) | ((unsigned int)f2bf(p[1]) << 16);
        v.y = (unsigned int)f2bf(p[2]) | ((unsigned int)f2bf(p[3]) << 16);
        *(uint2*)(ps + pb * 72 + r0) = v;
    }
    __syncthreads();

    // o-phase: wave handles ct = w*2, w*2+1
    const unsigned short* oTn = oT0 + (size_t)n * C * R;
    s16x8 ap[2];
#pragma unroll
    for (int kt = 0; kt < 2; ++kt)
        ap[kt] = *(const s16x8*)(ps + m * 72 + kt * 32 + g * 8);
    f32x4 aco[2];
#pragma unroll
    for (int i = 0; i < 2; ++i) {
        aco[i] = (f32x4){0.f, 0.f, 0.f, 0.f};
        const int ct = w * 2 + i;
#pragma unroll
        for (int kt = 0; kt < 2; ++kt) {
            const s16x8 bfr = *(const s16x8*)(oTn + (size_t)(ct * 16 + m) * R + kt * 32 + g * 8);
            aco[i] = __builtin_amdgcn_mfma_f32_16x16x32_bf16(ap[kt], bfr, aco[i], 0, 0, 0);
        }
    }
#pragma unroll
    for (int i = 0; i < 2; ++i)
#pragma unroll
        for (int j = 0; j < 4; ++j) {
            const int row = bt + g * 4 + j;
            h1[((size_t)row * NN + n) * C + (w * 2 + i) * 16 + m] = f2bf(aco[i][j]);
        }
}

// ---------------------------------------------------------------------------
// Generic CP level, 4 waves/block (wave = quadrant). Used for level 1.
// Grid = NN * 32, n-major.
// ---------------------------------------------------------------------------
template<int NN, int GIN>
__global__ __launch_bounds__(256) void cp_level_mfma4(
    const unsigned short* __restrict__ hin,  // (B, GIN*GIN, C) bf16
    const unsigned short* __restrict__ fT,   // (NN, 4, R, C) bf16
    const unsigned short* __restrict__ oT,   // (NN, C, R) bf16
    unsigned short* __restrict__ hout)       // (B, NN, C) bf16
{
    constexpr int NIN = GIN * GIN;
    constexpr int G2  = GIN / 2;
    __shared__ __align__(16) float us[4 * 16 * 68];
    __shared__ __align__(16) unsigned short ps[16 * 72];

    const int bi = blockIdx.x;
    const int n = bi >> 5, btile = bi & 31;
    const int t = threadIdx.x, w = t >> 6, lane = t & 63;
    const int m = lane & 15, g = lane >> 4;
    const int bt = btile * 16;
    const int y1 = n / G2, x1 = n % G2;
    const int q = w;

    const int pidx = (2 * y1 + (q >> 1)) * GIN + 2 * x1 + (q & 1);
    const unsigned short* xq = hin + ((size_t)(bt + m) * NIN + pidx) * C;
    const unsigned short* fq = fT + (size_t)(n * 4 + q) * R * C;

    f32x4 acc_u[4];
#pragma unroll
    for (int nt = 0; nt < 4; ++nt) acc_u[nt] = (f32x4){0.f, 0.f, 0.f, 0.f};
#pragma unroll
    for (int kt = 0; kt < 4; ++kt) {
        const int koff = kt * 32 + g * 8;
        const s16x8 a = *(const s16x8*)(xq + koff);
#pragma unroll
        for (int nt = 0; nt < 4; ++nt) {
            const s16x8 bfr = *(const s16x8*)(fq + (size_t)(nt * 16 + m) * C + koff);
            acc_u[nt] = __builtin_amdgcn_mfma_f32_16x16x32_bf16(a, bfr, acc_u[nt], 0, 0, 0);
        }
    }
#pragma unroll
    for (int nt = 0; nt < 4; ++nt)
#pragma unroll
        for (int j = 0; j < 4; ++j)
            us[(q * 16 + g * 4 + j) * 68 + nt * 16 + m] = acc_u[nt][j];
    __syncthreads();

    {
        const int pb = t >> 4, r0 = (t & 15) * 4;
        const f32x4 u0 = *(const f32x4*)(us + (0 * 16 + pb) * 68 + r0);
        const f32x4 u1 = *(const f32x4*)(us + (1 * 16 + pb) * 68 + r0);
        const f32x4 u2 = *(const f32x4*)(us + (2 * 16 + pb) * 68 + r0);
        const f32x4 u3 = *(const f32x4*)(us + (3 * 16 + pb) * 68 + r0);
        const f32x4 p = u0 * u1 * u2 * u3;
        uint2 v;
        v.x = (unsigned int)f2bf(p[0]) | ((unsigned int)f2bf(p[1]) << 16);
        v.y = (unsigned int)f2bf(p[2]) | ((unsigned int)f2bf(p[3]) << 16);
        *(uint2*)(ps + pb * 72 + r0) = v;
    }
    __syncthreads();

    const unsigned short* oTn = oT + (size_t)n * C * R;
    s16x8 ap[2];
#pragma unroll
    for (int kt = 0; kt < 2; ++kt)
        ap[kt] = *(const s16x8*)(ps + m * 72 + kt * 32 + g * 8);
    f32x4 aco[2];
#pragma unroll
    for (int i = 0; i < 2; ++i) {
        aco[i] = (f32x4){0.f, 0.f, 0.f, 0.f};
        const int ct = w * 2 + i;
#pragma unroll
        for (int kt = 0; kt < 2; ++kt) {
            const s16x8 bfr = *(const s16x8*)(oTn + (size_t)(ct * 16 + m) * R + kt * 32 + g * 8);
            aco[i] = __builtin_amdgcn_mfma_f32_16x16x32_bf16(ap[kt], bfr, aco[i], 0, 0, 0);
        }
    }
#pragma unroll
    for (int i = 0; i < 2; ++i)
#pragma unroll
        for (int j = 0; j < 4; ++j) {
            const int row = bt + g * 4 + j;
            hout[((size_t)row * NN + n) * C + (w * 2 + i) * 16 + m] = f2bf(aco[i][j]);
        }
}

// ---------------------------------------------------------------------------
// Tail: level2 + level3 + LayerNorm + head + L2norm, one block = 16 batches.
// LDS-resident h3/h4; 4 waves. Grid = 32 blocks.
// ---------------------------------------------------------------------------
__global__ __launch_bounds__(256) void tail_kernel(
    const unsigned short* __restrict__ h2,    // (B,16,128) bf16
    const unsigned short* __restrict__ fT2,   // 16 slices (64 x 128)
    const unsigned short* __restrict__ oT2,   // 4 slices (128 x 64)
    const unsigned short* __restrict__ fT3,   // 4 slices (64 x 128)
    const unsigned short* __restrict__ oT3,   // 1 slice (128 x 64)
    const float* __restrict__ gamma, const float* __restrict__ beta,
    const unsigned short* __restrict__ WhT,   // (512 x 128) bf16
    const float* __restrict__ bh,             // (512)
    float* __restrict__ out)                  // (B,512) fp32
{
    __shared__ __align__(16) float          us3[4 * 16 * 68];   // 17408
    __shared__ __align__(16) unsigned short ps2[4 * 16 * 72];   //  9216
    __shared__ __align__(16) unsigned short ps3[16 * 72];       //  2304
    __shared__ __align__(16) unsigned short h3s[16 * 4 * 136];  // 17408
    __shared__ __align__(16) float          h4s[16 * 132];      //  8448
    __shared__ __align__(16) unsigned short hns[16 * 136];      //  4352
    __shared__ float red[16 * 4];                               //   256

    const int bt = blockIdx.x * 16;
    const int t = threadIdx.x, w = t >> 6, lane = t & 63;
    const int m = lane & 15, g = lane >> 4;

    // ================= Level 2: wave w = node n2 (0..3) =================
    {
        const int n2 = w;
        const int y1 = n2 >> 1, x1 = n2 & 1;
        f32x4 acc_u[4][4];
#pragma unroll
        for (int q = 0; q < 4; ++q)
#pragma unroll
            for (int nt = 0; nt < 4; ++nt) acc_u[q][nt] = (f32x4){0.f, 0.f, 0.f, 0.f};
#pragma unroll
        for (int q = 0; q < 4; ++q) {
            const int pidx = (2 * y1 + (q >> 1)) * 4 + 2 * x1 + (q & 1);
            const unsigned short* xq = h2 + ((size_t)(bt + m) * 16 + pidx) * C;
            const unsigned short* fq = fT2 + (size_t)(n2 * 4 + q) * R * C;
#pragma unroll
            for (int kt = 0; kt < 4; ++kt) {
                const int koff = kt * 32 + g * 8;
                const s16x8 a = *(const s16x8*)(xq + koff);
#pragma unroll
                for (int nt = 0; nt < 4; ++nt) {
                    const s16x8 bfr = *(const s16x8*)(fq + (size_t)(nt * 16 + m) * C + koff);
                    acc_u[q][nt] = __builtin_amdgcn_mfma_f32_16x16x32_bf16(a, bfr, acc_u[q][nt], 0, 0, 0);
                }
            }
        }
        f32x4 p[4];
#pragma unroll
        for (int nt = 0; nt < 4; ++nt)
            p[nt] = acc_u[0][nt] * acc_u[1][nt] * acc_u[2][nt] * acc_u[3][nt];
        unsigned short* myps = ps2 + w * 16 * 72;
#pragma unroll
        for (int nt = 0; nt < 4; ++nt)
#pragma unroll
            for (int j = 0; j < 4; ++j)
                myps[(g * 4 + j) * 72 + nt * 16 + m] = f2bf(p[nt][j]);

        // o-phase (per-wave node)
        f32x4 aco[8];
#pragma unroll
        for (int ct = 0; ct < 8; ++ct) aco[ct] = (f32x4){0.f, 0.f, 0.f, 0.f};
        const unsigned short* oTn = oT2 + (size_t)n2 * C * R;
#pragma unroll
        for (int kt = 0; kt < 2; ++kt) {
            const int koff = kt * 32 + g * 8;
            const s16x8 a = *(const s16x8*)(myps + m * 72 + koff);
#pragma unroll
            for (int ct = 0; ct < 8; ++ct) {
                const s16x8 bfr = *(const s16x8*)(oTn + (size_t)(ct * 16 + m) * R + koff);
                aco[ct] = __builtin_amdgcn_mfma_f32_16x16x32_bf16(a, bfr, aco[ct], 0, 0, 0);
            }
        }
        // h3s[b][n2][c]
#pragma unroll
        for (int ct = 0; ct < 8; ++ct)
#pragma unroll
            for (int j = 0; j < 4; ++j)
                h3s[((g * 4 + j) * 4 + n2) * 136 + ct * 16 + m] = f2bf(aco[ct][j]);
    }
    __syncthreads();

    // ================= Level 3: wave w = quadrant q =================
    {
        const int q = w;
        const unsigned short* fq = fT3 + (size_t)q * R * C;
        f32x4 acc_u[4];
#pragma unroll
        for (int nt = 0; nt < 4; ++nt) acc_u[nt] = (f32x4){0.f, 0.f, 0.f, 0.f};
#pragma unroll
        for (int kt = 0; kt < 4; ++kt) {
            const int koff = kt * 32 + g * 8;
            const s16x8 a = *(const s16x8*)(h3s + (m * 4 + q) * 136 + koff);
#pragma unroll
            for (int nt = 0; nt < 4; ++nt) {
                const s16x8 bfr = *(const s16x8*)(fq + (size_t)(nt * 16 + m) * C + koff);
                acc_u[nt] = __builtin_amdgcn_mfma_f32_16x16x32_bf16(a, bfr, acc_u[nt], 0, 0, 0);
            }
        }
#pragma unroll
        for (int nt = 0; nt < 4; ++nt)
#pragma unroll
            for (int j = 0; j < 4; ++j)
                us3[(q * 16 + g * 4 + j) * 68 + nt * 16 + m] = acc_u[nt][j];
    }
    __syncthreads();
    {
        const int pb = t >> 4, r0 = (t & 15) * 4;
        const f32x4 u0 = *(const f32x4*)(us3 + (0 * 16 + pb) * 68 + r0);
        const f32x4 u1 = *(const f32x4*)(us3 + (1 * 16 + pb) * 68 + r0);
        const f32x4 u2 = *(const f32x4*)(us3 + (2 * 16 + pb) * 68 + r0);
        const f32x4 u3 = *(const f32x4*)(us3 + (3 * 16 + pb) * 68 + r0);
        const f32x4 p = u0 * u1 * u2 * u3;
        uint2 v;
        v.x = (unsigned int)f2bf(p[0]) | ((unsigned int)f2bf(p[1]) << 16);
        v.y = (unsigned int)f2bf(p[2]) | ((unsigned int)f2bf(p[3]) << 16);
        *(uint2*)(ps3 + pb * 72 + r0) = v;
    }
    __syncthreads();
    {
        // o-phase: wave handles ct = w*2, w*2+1 -> h4s fp32
        s16x8 ap[2];
#pragma unroll
        for (int kt = 0; kt < 2; ++kt)
            ap[kt] = *(const s16x8*)(ps3 + m * 72 + kt * 32 + g * 8);
#pragma unroll
        for (int i = 0; i < 2; ++i) {
            f32x4 aco = (f32x4){0.f, 0.f, 0.f, 0.f};
            const int ct = w * 2 + i;
#pragma unroll
            for (int kt = 0; kt < 2; ++kt) {
                const s16x8 bfr = *(const s16x8*)(oT3 + (size_t)(ct * 16 + m) * R + kt * 32 + g * 8);
                aco = __builtin_amdgcn_mfma_f32_16x16x32_bf16(ap[kt], bfr, aco, 0, 0, 0);
            }
#pragma unroll
            for (int j = 0; j < 4; ++j)
                h4s[(g * 4 + j) * 132 + ct * 16 + m] = aco[j];
        }
    }
    __syncthreads();

    // ================= LayerNorm: row rb = w*4+g, 16 lanes (m) x 8 cols ====
    {
        const int rb = w * 4 + g;
        const int c0 = m * 8;
        const f32x4 v0 = *(const f32x4*)(h4s + rb * 132 + c0);
        const f32x4 v1 = *(const f32x4*)(h4s + rb * 132 + c0 + 4);
        float s  = v0[0] + v0[1] + v0[2] + v0[3] + v1[0] + v1[1] + v1[2] + v1[3];
        float ss = v0[0]*v0[0] + v0[1]*v0[1] + v0[2]*v0[2] + v0[3]*v0[3]
                 + v1[0]*v1[0] + v1[1]*v1[1] + v1[2]*v1[2] + v1[3]*v1[3];
#pragma unroll
        for (int off = 1; off < 16; off <<= 1) {
            s  += __shfl_xor(s, off);
            ss += __shfl_xor(ss, off);
        }
        const float mu   = s * (1.f / C);
        const float var  = ss * (1.f / C) - mu * mu;
        const float rstd = rsqrtf(var + 1e-5f);
        const f32x4 ga0 = *(const f32x4*)(gamma + c0);
        const f32x4 ga1 = *(const f32x4*)(gamma + c0 + 4);
        const f32x4 be0 = *(const f32x4*)(beta + c0);
        const f32x4 be1 = *(const f32x4*)(beta + c0 + 4);
        unsigned int o32[4];
        float hv[8];
#pragma unroll
        for (int k = 0; k < 4; ++k) hv[k]     = (v0[k] - mu) * rstd * ga0[k] + be0[k];
#pragma unroll
        for (int k = 0; k < 4; ++k) hv[4 + k] = (v1[k] - mu) * rstd * ga1[k] + be1[k];
#pragma unroll
        for (int k = 0; k < 4; ++k)
            o32[k] = (unsigned int)f2bf(hv[2*k]) | ((unsigned int)f2bf(hv[2*k+1]) << 16);
        *(uint4*)(hns + rb * 136 + c0) = *(uint4*)o32;
    }
    __syncthreads();

    // ================= Head GEMM (16x128)@(128x512) + L2 norm =============
    {
        f32x4 acc[8];
#pragma unroll
        for (int nt = 0; nt < 8; ++nt) {
            const int e = w * 128 + nt * 16 + m;
            const float bv = bh[e];
            acc[nt] = (f32x4){bv, bv, bv, bv};
        }
#pragma unroll
        for (int kt = 0; kt < 4; ++kt) {
            const int koff = kt * 32 + g * 8;
            const s16x8 a = *(const s16x8*)(hns + m * 136 + koff);
#pragma unroll
            for (int nt = 0; nt < 8; ++nt) {
                const int e = w * 128 + nt * 16 + m;
                const s16x8 bfr = *(const s16x8*)(WhT + (size_t)e * 128 + koff);
                acc[nt] = __builtin_amdgcn_mfma_f32_16x16x32_bf16(a, bfr, acc[nt], 0, 0, 0);
            }
        }
        // partial row-sumsq within this wave's 128 cols
        float sq[4];
#pragma unroll
        for (int j = 0; j < 4; ++j) {
            float s = 0.f;
#pragma unroll
            for (int nt = 0; nt < 8; ++nt) s += acc[nt][j] * acc[nt][j];
#pragma unroll
            for (int off = 1; off < 16; off <<= 1) s += __shfl_xor(s, off);
            sq[j] = s;
        }
        if (m == 0) {
#pragma unroll
            for (int j = 0; j < 4; ++j) red[(g * 4 + j) * 4 + w] = sq[j];
        }
        __syncthreads();
#pragma unroll
        for (int j = 0; j < 4; ++j) {
            const int row = g * 4 + j;
            const float tot = red[row * 4 + 0] + red[row * 4 + 1]
                            + red[row * 4 + 2] + red[row * 4 + 3];
            const float inv = 1.f / fmaxf(sqrtf(tot), 1e-12f);
#pragma unroll
            for (int nt = 0; nt < 8; ++nt) {
                const int e = w * 128 + nt * 16 + m;
                out[(size_t)(bt + row) * E + e] = acc[nt][j] * inv;
            }
        }
    }
}

// ---------------------------------------------------------------------------
extern "C" void kernel_launch(void* const* d_in, const int* in_sizes, int n_in,
                              void* d_out, int out_size, void* d_ws, size_t ws_size,
                              hipStream_t stream) {
    const float* x     = (const float*)d_in[0];
    const float* Wp    = (const float*)d_in[1];
    const float* bp    = (const float*)d_in[2];
    const float* pos   = (const float*)d_in[3];
    const float* gamma = (const float*)d_in[4];
    const float* beta  = (const float*)d_in[5];
    const float* Wh    = (const float*)d_in[6];
    const float* bh    = (const float*)d_in[7];
    const float* f0    = (const float*)d_in[8];
    const float* o0    = (const float*)d_in[9];
    const float* f1    = (const float*)d_in[10];
    const float* o1    = (const float*)d_in[11];
    const float* f2    = (const float*)d_in[12];
    const float* o2    = (const float*)d_in[13];
    const float* f3    = (const float*)d_in[14];
    const float* o3    = (const float*)d_in[15];
    float* out = (float*)d_out;

    // workspace layout (bf16 elements unless noted)
    unsigned short* h1  = (unsigned short*)d_ws;           //  4,194,304
    unsigned short* h2  = h1 + (size_t)4194304;            //  1,048,576
    unsigned short* fT  = h2 + (size_t)1048576;            //  2,785,280 (340 slices)
    unsigned short* oT  = fT + (size_t)2785280;            //    696,320 (85 slices)
    unsigned short* Wpb = oT + (size_t)696320;             //      8,192
    unsigned short* WfT = Wpb + (size_t)8192;              //  1,048,576
    unsigned short* WhT = WfT + (size_t)1048576;           //     65,536
    float*          pff = (float*)(WhT + 65536);           //     16,384 fp32

    unsigned short* fT0 = fT;
    unsigned short* fT1 = fT + (size_t)256 * 8192;
    unsigned short* fT2 = fT + (size_t)320 * 8192;
    unsigned short* fT3 = fT + (size_t)336 * 8192;
    unsigned short* oT0 = oT;
    unsigned short* oT1 = oT + (size_t)64 * 8192;
    unsigned short* oT2 = oT + (size_t)80 * 8192;
    unsigned short* oT3 = oT + (size_t)84 * 8192;

    prep_kernel<<<434, 256, 0, stream>>>(f0, f1, f2, f3, o0, o1, o2, o3,
                                         Wh, Wp, fT, oT, WhT, Wpb);
    wft_pf_kernel<<<512, 64, 0, stream>>>(fT0, Wpb, pos, bp, WfT, pff);

    cp_level0_fused<<<64 * 32, 256, 0, stream>>>(x, WfT, pff, oT0, h1);
    cp_level_mfma4<16, 8><<<16 * 32, 256, 0, stream>>>(h1, fT1, oT1, h2);
    tail_kernel<<<32, 256, 0, stream>>>(h2, fT2, oT2, fT3, oT3,
                                        gamma, beta, WhT, bh, out);
}

// Round 7
// 156.533 us; speedup vs baseline: 2.4056x; 1.0574x over previous
//
#include <hip/hip_runtime.h>
#include <hip/hip_bf16.h>

// Problem constants
#define BATCH     512
#define IMG       128
#define PS        8
#define GRID_P    16      // IMG/PS
#define NP        256     // GRID_P*GRID_P
#define C         128     // BOND_DIM
#define R         64      // CP_RANK
#define E         512     // EMBED_DIM

typedef float f32x4 __attribute__((ext_vector_type(4)));
typedef short s16x8 __attribute__((ext_vector_type(8)));

__device__ __forceinline__ unsigned short f2bf(float x) {
    unsigned int u = __float_as_uint(x);
    u += 0x7fffu + ((u >> 16) & 1u);          // RNE
    return (unsigned short)(u >> 16);
}
__device__ __forceinline__ float bf2f(unsigned short h) {
    return __uint_as_float(((unsigned int)h) << 16);
}

// ---------------------------------------------------------------------------
// prep_all (ONE launch, 433 blocks):
//   bi <256 : WfT+pf for level-0 slice (n0,q)=bi directly from f0 (in-LDS
//             transpose; fT0 never materialized).
//             WfT[r][k] = sum_c Wp[k][c]*f0[bi][c][r]  (64x64 bf16)
//             pf[r]     = sum_c (pos[p][c]+bp[c])*f0[bi][c][r]
//   bi 256..339 : f1/f2/f3 slices (128c x 64r) fp32 -> fTL (64r x 128c) bf16
//   bi 340..424 : o slices (64r x 128c) fp32 -> oT (128c x 64r) bf16
//   bi 425..432 : Wh (128c x 512e) -> WhT (512e x 128c) bf16
// ---------------------------------------------------------------------------
__global__ __launch_bounds__(256) void prep_all_kernel(
    const float* __restrict__ f0, const float* __restrict__ f1,
    const float* __restrict__ f2, const float* __restrict__ f3,
    const float* __restrict__ o0, const float* __restrict__ o1,
    const float* __restrict__ o2, const float* __restrict__ o3,
    const float* __restrict__ Wh, const float* __restrict__ Wp,
    const float* __restrict__ pos, const float* __restrict__ bp,
    unsigned short* __restrict__ fTL, unsigned short* __restrict__ oT,
    unsigned short* __restrict__ WhT, unsigned short* __restrict__ WfT,
    float* __restrict__ pf)
{
    __shared__ float ls[128 * 68];    // 34.8 KB
    __shared__ float red[64 * 4];
    const int bi = blockIdx.x, t = threadIdx.x;

    if (bi < 256) {
        // ---- WfT + pf from f0 slice (128c x 64r) ----
        const float* src = f0 + (size_t)bi * 8192;
#pragma unroll
        for (int i = 0; i < 8; ++i) {
            const int fi = (t + 256 * i) * 4;
            const int c = fi >> 6, r = fi & 63;      // in[c][r]
            *(float4*)(ls + c * 68 + r) = *(const float4*)(src + fi);
        }
        __syncthreads();

        const int w = t >> 6, lane = t & 63;
        const int m = lane & 15, g = lane >> 4;

        // MFMA: M=64 r (wave w = m-tile), N=64 k, K=128 c
        f32x4 acc[4];
#pragma unroll
        for (int nt = 0; nt < 4; ++nt) acc[nt] = (f32x4){0.f, 0.f, 0.f, 0.f};
#pragma unroll
        for (int kt = 0; kt < 4; ++kt) {
            s16x8 afr;
#pragma unroll
            for (int e = 0; e < 8; ++e)
                afr[e] = (short)f2bf(ls[(kt * 32 + g * 8 + e) * 68 + w * 16 + m]);
#pragma unroll
            for (int nt = 0; nt < 4; ++nt) {
                const float* wr = Wp + (size_t)(nt * 16 + m) * 128 + kt * 32 + g * 8;
                const float4 b0 = *(const float4*)wr;
                const float4 b1 = *(const float4*)(wr + 4);
                s16x8 bfr;
                bfr[0] = (short)f2bf(b0.x); bfr[1] = (short)f2bf(b0.y);
                bfr[2] = (short)f2bf(b0.z); bfr[3] = (short)f2bf(b0.w);
                bfr[4] = (short)f2bf(b1.x); bfr[5] = (short)f2bf(b1.y);
                bfr[6] = (short)f2bf(b1.z); bfr[7] = (short)f2bf(b1.w);
                acc[nt] = __builtin_amdgcn_mfma_f32_16x16x32_bf16(afr, bfr, acc[nt], 0, 0, 0);
            }
        }
        unsigned short* D = WfT + (size_t)bi * 4096;
#pragma unroll
        for (int nt = 0; nt < 4; ++nt)
#pragma unroll
            for (int j = 0; j < 4; ++j)
                D[(size_t)(w * 16 + g * 4 + j) * 64 + nt * 16 + m] = f2bf(acc[nt][j]);

        // pf partials: thread (r = t&63, half = t>>6) covers 32 c's
        {
            const int r = t & 63, half = t >> 6;
            const int n0 = bi >> 2, q = bi & 3;
            const int pp = (2 * (n0 >> 3) + (q >> 1)) * GRID_P + 2 * (n0 & 7) + (q & 1);
            const float* posr = pos + (size_t)pp * C;
            float s = 0.f;
#pragma unroll 8
            for (int e = 0; e < 32; ++e) {
                const int c = half * 32 + e;
                s += (posr[c] + bp[c]) * ls[c * 68 + r];
            }
            red[r * 4 + half] = s;
        }
        __syncthreads();
        if (t < 64)
            pf[bi * 64 + t] = red[t * 4 + 0] + red[t * 4 + 1] + red[t * 4 + 2] + red[t * 4 + 3];
    } else if (bi < 340) {
        // ---- f1/f2/f3 transpose: slice ti -> fTL + ti*8192 ----
        const int ti = bi - 256;
        const float* src;
        if      (ti < 64) src = f1 + (size_t)ti * 8192;
        else if (ti < 80) src = f2 + (size_t)(ti - 64) * 8192;
        else              src = f3 + (size_t)(ti - 80) * 8192;
        unsigned short* dst = fTL + (size_t)ti * 8192;
#pragma unroll
        for (int i = 0; i < 8; ++i) {
            const int fi = (t + 256 * i) * 4;
            const int c = fi >> 6, r = fi & 63;
            *(float4*)(ls + c * 68 + r) = *(const float4*)(src + fi);
        }
        __syncthreads();
        const int rr = t >> 2, seg = t & 3;
        unsigned int* d32 = (unsigned int*)(dst + rr * 128 + seg * 32);
#pragma unroll
        for (int ii = 0; ii < 16; ++ii) {
            const int c = seg * 32 + ii * 2;
            const unsigned int lo = f2bf(ls[c * 68 + rr]);
            const unsigned int hi = f2bf(ls[(c + 1) * 68 + rr]);
            d32[ii] = lo | (hi << 16);
        }
    } else if (bi < 425) {
        // ---- o transpose ----
        const int oi = bi - 340;
        const float* src;
        if      (oi < 64) src = o0 + (size_t)oi * 8192;
        else if (oi < 80) src = o1 + (size_t)(oi - 64) * 8192;
        else if (oi < 84) src = o2 + (size_t)(oi - 80) * 8192;
        else              src = o3 + (size_t)(oi - 84) * 8192;
        unsigned short* dst = oT + (size_t)oi * 8192;
#pragma unroll
        for (int i = 0; i < 8; ++i) {
            const int fi = (t + 256 * i) * 4;
            const int r = fi >> 7, c = fi & 127;
            *(float4*)(ls + r * 132 + c) = *(const float4*)(src + fi);
        }
        __syncthreads();
        const int cc = t >> 1, seg = t & 1;
        unsigned int* d32 = (unsigned int*)(dst + cc * 64 + seg * 32);
#pragma unroll
        for (int ii = 0; ii < 16; ++ii) {
            const int r = seg * 32 + ii * 2;
            const unsigned int lo = f2bf(ls[r * 132 + cc]);
            const unsigned int hi = f2bf(ls[(r + 1) * 132 + cc]);
            d32[ii] = lo | (hi << 16);
        }
    } else {
        // ---- WhT ----
        const int j = bi - 425;
#pragma unroll
        for (int i = 0; i < 8; ++i) {
            const int fi = (t + 256 * i) * 4;
            const int c = fi >> 6, e = fi & 63;
            *(float4*)(ls + c * 68 + e) = *(const float4*)(Wh + (size_t)c * E + j * 64 + e);
        }
        __syncthreads();
        const int rr = t >> 2, seg = t & 3;
        unsigned int* d32 = (unsigned int*)(WhT + (size_t)(j * 64 + rr) * 128 + seg * 32);
#pragma unroll
        for (int ii = 0; ii < 16; ++ii) {
            const int c = seg * 32 + ii * 2;
            const unsigned int lo = f2bf(ls[c * 68 + rr]);
            const unsigned int hi = f2bf(ls[(c + 1) * 68 + rr]);
            d32[ii] = lo | (hi << 16);
        }
    }
}

// ---------------------------------------------------------------------------
// Fused level0+level1: block = (n1 parent, 16 batches), grid = 16*32 n1-major.
// Wave w = child node n0 = quadrant q1=w of n1.
//   Level0 (all in-wave, wave-private LDS, no barrier): pixel A-frags
//   (patch row = K-layout) @ WfT +pf -> u; p = prod in regs; ps roundtrip;
//   o-phase -> h1 tile staged in wave-private LDS.
//   Level1: own h1 tile IS the A-operand; u1 -> us (barrier) -> p (barrier)
//   -> o-phase ct-split -> h2.
// ---------------------------------------------------------------------------
__global__ __launch_bounds__(256) void level01_fused(
    const float* __restrict__ x,              // (B,1,128,128)
    const unsigned short* __restrict__ WfT,   // 256 slices (64r x 64k)
    const float* __restrict__ pf,             // (256 x 64) fp32
    const unsigned short* __restrict__ oT,    // oT0 at slice n0, oT1 at 64+n1
    const unsigned short* __restrict__ fT1,   // 64 slices (64r x 128c)
    unsigned short* __restrict__ h2)          // (B,16,128) bf16
{
    __shared__ __align__(16) float          us1[4 * 16 * 68];   // 17408 B
    __shared__ __align__(16) unsigned short ps0[4 * 16 * 72];   //  9216 B
    __shared__ __align__(16) unsigned short ps1[16 * 72];       //  2304 B
    __shared__ __align__(16) unsigned short h1s[4 * 16 * 136];  // 17408 B

    const int bi = blockIdx.x;
    const int n1 = bi >> 5, btile = bi & 31;
    const int t = threadIdx.x, w = t >> 6, lane = t & 63;
    const int m = lane & 15, g = lane >> 4;
    const int bt = btile * 16;
    const int b  = bt + m;

    const int n0 = (2 * (n1 >> 2) + (w >> 1)) * 8 + 2 * (n1 & 3) + (w & 1);
    const int y0 = n0 >> 3, x0 = n0 & 7;

    // ---- level0 pixel A-fragments (4 quadrants x K=64) ----
    s16x8 a[4][2];
#pragma unroll
    for (int q = 0; q < 4; ++q) {
        const int py = (2 * y0 + (q >> 1)) * PS;
        const int px = (2 * x0 + (q & 1)) * PS;
#pragma unroll
        for (int kt = 0; kt < 2; ++kt) {
            const float* src = x + ((size_t)b * IMG + py + kt * 4 + g) * IMG + px;
            const float4 p0 = *(const float4*)src;
            const float4 p1 = *(const float4*)(src + 4);
            s16x8 v;
            v[0] = (short)f2bf(p0.x); v[1] = (short)f2bf(p0.y);
            v[2] = (short)f2bf(p0.z); v[3] = (short)f2bf(p0.w);
            v[4] = (short)f2bf(p1.x); v[5] = (short)f2bf(p1.y);
            v[6] = (short)f2bf(p1.z); v[7] = (short)f2bf(p1.w);
            a[q][kt] = v;
        }
    }

    // ---- level0 u-phase (+pf init), all 4 quadrants in-wave ----
    f32x4 accu[4][4];
#pragma unroll
    for (int q = 0; q < 4; ++q) {
        const float* pfq = pf + (size_t)(n0 * 4 + q) * 64;
#pragma unroll
        for (int nt = 0; nt < 4; ++nt) {
            const float pv = pfq[nt * 16 + m];
            accu[q][nt] = (f32x4){pv, pv, pv, pv};
        }
    }
#pragma unroll
    for (int q = 0; q < 4; ++q) {
        const unsigned short* Wq = WfT + (size_t)(n0 * 4 + q) * 4096;
#pragma unroll
        for (int kt = 0; kt < 2; ++kt) {
            const int koff = kt * 32 + g * 8;
#pragma unroll
            for (int nt = 0; nt < 4; ++nt) {
                const s16x8 bfr = *(const s16x8*)(Wq + (size_t)(nt * 16 + m) * 64 + koff);
                accu[q][nt] = __builtin_amdgcn_mfma_f32_16x16x32_bf16(a[q][kt], bfr, accu[q][nt], 0, 0, 0);
            }
        }
    }

    // ---- level0 p-phase (regs) + wave-private ps roundtrip ----
    unsigned short* myps = ps0 + w * (16 * 72);
#pragma unroll
    for (int nt = 0; nt < 4; ++nt) {
        const f32x4 pr = accu[0][nt] * accu[1][nt] * accu[2][nt] * accu[3][nt];
#pragma unroll
        for (int j = 0; j < 4; ++j)
            myps[(g * 4 + j) * 72 + nt * 16 + m] = f2bf(pr[j]);
    }

    // ---- level0 o-phase (full 128c, in-wave) -> h1 tile in wave-private LDS
    {
        s16x8 ap[2];
#pragma unroll
        for (int kt = 0; kt < 2; ++kt)
            ap[kt] = *(const s16x8*)(myps + m * 72 + kt * 32 + g * 8);
        const unsigned short* oTn = oT + (size_t)n0 * 8192;
        unsigned short* myh = h1s + w * (16 * 136);
#pragma unroll
        for (int ct = 0; ct < 8; ++ct) {
            f32x4 aco = (f32x4){0.f, 0.f, 0.f, 0.f};
#pragma unroll
            for (int kt = 0; kt < 2; ++kt) {
                const s16x8 bfr = *(const s16x8*)(oTn + (size_t)(ct * 16 + m) * 64 + kt * 32 + g * 8);
                aco = __builtin_amdgcn_mfma_f32_16x16x32_bf16(ap[kt], bfr, aco, 0, 0, 0);
            }
#pragma unroll
            for (int j = 0; j < 4; ++j)
                myh[(g * 4 + j) * 136 + ct * 16 + m] = f2bf(aco[j]);
        }
    }

    // ---- level1 u-phase: A = own h1 tile (wave-private, no barrier) ----
    {
        const unsigned short* myh = h1s + w * (16 * 136);
        const unsigned short* fq = fT1 + (size_t)(n1 * 4 + w) * 8192;
        f32x4 au[4];
#pragma unroll
        for (int nt = 0; nt < 4; ++nt) au[nt] = (f32x4){0.f, 0.f, 0.f, 0.f};
#pragma unroll
        for (int kt = 0; kt < 4; ++kt) {
            const int koff = kt * 32 + g * 8;
            const s16x8 afr = *(const s16x8*)(myh + m * 136 + koff);
#pragma unroll
            for (int nt = 0; nt < 4; ++nt) {
                const s16x8 bfr = *(const s16x8*)(fq + (size_t)(nt * 16 + m) * 128 + koff);
                au[nt] = __builtin_amdgcn_mfma_f32_16x16x32_bf16(afr, bfr, au[nt], 0, 0, 0);
            }
        }
#pragma unroll
        for (int nt = 0; nt < 4; ++nt)
#pragma unroll
            for (int j = 0; j < 4; ++j)
                us1[(w * 16 + g * 4 + j) * 68 + nt * 16 + m] = au[nt][j];
    }
    __syncthreads();

    // ---- level1 p-phase (block-wide) ----
    {
        const int pb = t >> 4, r0 = (t & 15) * 4;
        const f32x4 u0 = *(const f32x4*)(us1 + (0 * 16 + pb) * 68 + r0);
        const f32x4 u1 = *(const f32x4*)(us1 + (1 * 16 + pb) * 68 + r0);
        const f32x4 u2 = *(const f32x4*)(us1 + (2 * 16 + pb) * 68 + r0);
        const f32x4 u3 = *(const f32x4*)(us1 + (3 * 16 + pb) * 68 + r0);
        const f32x4 p = u0 * u1 * u2 * u3;
        uint2 v;
        v.x = (unsigned int)f2bf(p[0]) | ((unsigned int)f2bf(p[1]) << 16);
        v.y = (unsigned int)f2bf(p[2]) | ((unsigned int)f2bf(p[3]) << 16);
        *(uint2*)(ps1 + pb * 72 + r0) = v;
    }
    __syncthreads();

    // ---- level1 o-phase: wave handles ct = 2w, 2w+1 -> h2 ----
    {
        s16x8 ap[2];
#pragma unroll
        for (int kt = 0; kt < 2; ++kt)
            ap[kt] = *(const s16x8*)(ps1 + m * 72 + kt * 32 + g * 8);
        const unsigned short* oTn = oT + (size_t)(64 + n1) * 8192;
#pragma unroll
        for (int i = 0; i < 2; ++i) {
            const int ct = w * 2 + i;
            f32x4 aco = (f32x4){0.f, 0.f, 0.f, 0.f};
#pragma unroll
            for (int kt = 0; kt < 2; ++kt) {
                const s16x8 bfr = *(const s16x8*)(oTn + (size_t)(ct * 16 + m) * 64 + kt * 32 + g * 8);
                aco = __builtin_amdgcn_mfma_f32_16x16x32_bf16(ap[kt], bfr, aco, 0, 0, 0);
            }
#pragma unroll
            for (int j = 0; j < 4; ++j)
                h2[((size_t)(bt + g * 4 + j) * 16 + n1) * C + ct * 16 + m] = f2bf(aco[j]);
        }
    }
}

// ---------------------------------------------------------------------------
// Tail: level2 + level3 + LayerNorm + head + L2norm, block = 16 batches.
// ---------------------------------------------------------------------------
__global__ __launch_bounds__(256) void tail_kernel(
    const unsigned short* __restrict__ h2,    // (B,16,128) bf16
    const unsigned short* __restrict__ fT2,   // 16 slices (64 x 128)
    const unsigned short* __restrict__ oT2,   // 4 slices (128 x 64)
    const unsigned short* __restrict__ fT3,   // 4 slices (64 x 128)
    const unsigned short* __restrict__ oT3,   // 1 slice (128 x 64)
    const float* __restrict__ gamma, const float* __restrict__ beta,
    const unsigned short* __restrict__ WhT,   // (512 x 128) bf16
    const float* __restrict__ bh,             // (512)
    float* __restrict__ out)                  // (B,512) fp32
{
    __shared__ __align__(16) float          us3[4 * 16 * 68];
    __shared__ __align__(16) unsigned short ps2[4 * 16 * 72];
    __shared__ __align__(16) unsigned short ps3[16 * 72];
    __shared__ __align__(16) unsigned short h3s[16 * 4 * 136];
    __shared__ __align__(16) float          h4s[16 * 132];
    __shared__ __align__(16) unsigned short hns[16 * 136];
    __shared__ float red[16 * 4];

    const int bt = blockIdx.x * 16;
    const int t = threadIdx.x, w = t >> 6, lane = t & 63;
    const int m = lane & 15, g = lane >> 4;

    // ===== Level 2: wave w = node n2 =====
    {
        const int n2 = w;
        const int y1 = n2 >> 1, x1 = n2 & 1;
        f32x4 acc_u[4][4];
#pragma unroll
        for (int q = 0; q < 4; ++q)
#pragma unroll
            for (int nt = 0; nt < 4; ++nt) acc_u[q][nt] = (f32x4){0.f, 0.f, 0.f, 0.f};
#pragma unroll
        for (int q = 0; q < 4; ++q) {
            const int pidx = (2 * y1 + (q >> 1)) * 4 + 2 * x1 + (q & 1);
            const unsigned short* xq = h2 + ((size_t)(bt + m) * 16 + pidx) * C;
            const unsigned short* fq = fT2 + (size_t)(n2 * 4 + q) * R * C;
#pragma unroll
            for (int kt = 0; kt < 4; ++kt) {
                const int koff = kt * 32 + g * 8;
                const s16x8 a = *(const s16x8*)(xq + koff);
#pragma unroll
                for (int nt = 0; nt < 4; ++nt) {
                    const s16x8 bfr = *(const s16x8*)(fq + (size_t)(nt * 16 + m) * C + koff);
                    acc_u[q][nt] = __builtin_amdgcn_mfma_f32_16x16x32_bf16(a, bfr, acc_u[q][nt], 0, 0, 0);
                }
            }
        }
        unsigned short* myps = ps2 + w * 16 * 72;
#pragma unroll
        for (int nt = 0; nt < 4; ++nt) {
            const f32x4 p = acc_u[0][nt] * acc_u[1][nt] * acc_u[2][nt] * acc_u[3][nt];
#pragma unroll
            for (int j = 0; j < 4; ++j)
                myps[(g * 4 + j) * 72 + nt * 16 + m] = f2bf(p[j]);
        }
        f32x4 aco[8];
#pragma unroll
        for (int ct = 0; ct < 8; ++ct) aco[ct] = (f32x4){0.f, 0.f, 0.f, 0.f};
        const unsigned short* oTn = oT2 + (size_t)n2 * C * R;
#pragma unroll
        for (int kt = 0; kt < 2; ++kt) {
            const int koff = kt * 32 + g * 8;
            const s16x8 a = *(const s16x8*)(myps + m * 72 + koff);
#pragma unroll
            for (int ct = 0; ct < 8; ++ct) {
                const s16x8 bfr = *(const s16x8*)(oTn + (size_t)(ct * 16 + m) * R + koff);
                aco[ct] = __builtin_amdgcn_mfma_f32_16x16x32_bf16(a, bfr, aco[ct], 0, 0, 0);
            }
        }
#pragma unroll
        for (int ct = 0; ct < 8; ++ct)
#pragma unroll
            for (int j = 0; j < 4; ++j)
                h3s[((g * 4 + j) * 4 + n2) * 136 + ct * 16 + m] = f2bf(aco[ct][j]);
    }
    __syncthreads();

    // ===== Level 3: wave w = quadrant q =====
    {
        const int q = w;
        const unsigned short* fq = fT3 + (size_t)q * R * C;
        f32x4 acc_u[4];
#pragma unroll
        for (int nt = 0; nt < 4; ++nt) acc_u[nt] = (f32x4){0.f, 0.f, 0.f, 0.f};
#pragma unroll
        for (int kt = 0; kt < 4; ++kt) {
            const int koff = kt * 32 + g * 8;
            const s16x8 a = *(const s16x8*)(h3s + (m * 4 + q) * 136 + koff);
#pragma unroll
            for (int nt = 0; nt < 4; ++nt) {
                const s16x8 bfr = *(const s16x8*)(fq + (size_t)(nt * 16 + m) * C + koff);
                acc_u[nt] = __builtin_amdgcn_mfma_f32_16x16x32_bf16(a, bfr, acc_u[nt], 0, 0, 0);
            }
        }
#pragma unroll
        for (int nt = 0; nt < 4; ++nt)
#pragma unroll
            for (int j = 0; j < 4; ++j)
                us3[(q * 16 + g * 4 + j) * 68 + nt * 16 + m] = acc_u[nt][j];
    }
    __syncthreads();
    {
        const int pb = t >> 4, r0 = (t & 15) * 4;
        const f32x4 u0 = *(const f32x4*)(us3 + (0 * 16 + pb) * 68 + r0);
        const f32x4 u1 = *(const f32x4*)(us3 + (1 * 16 + pb) * 68 + r0);
        const f32x4 u2 = *(const f32x4*)(us3 + (2 * 16 + pb) * 68 + r0);
        const f32x4 u3 = *(const f32x4*)(us3 + (3 * 16 + pb) * 68 + r0);
        const f32x4 p = u0 * u1 * u2 * u3;
        uint2 v;
        v.x = (unsigned int)f2bf(p[0]) | ((unsigned int)f2bf(p[1]) << 16);
        v.y = (unsigned int)f2bf(p[2]) | ((unsigned int)f2bf(p[3]) << 16);
        *(uint2*)(ps3 + pb * 72 + r0) = v;
    }
    __syncthreads();
    {
        s16x8 ap[2];
#pragma unroll
        for (int kt = 0; kt < 2; ++kt)
            ap[kt] = *(const s16x8*)(ps3 + m * 72 + kt * 32 + g * 8);
#pragma unroll
        for (int i = 0; i < 2; ++i) {
            f32x4 aco = (f32x4){0.f, 0.f, 0.f, 0.f};
            const int ct = w * 2 + i;
#pragma unroll
            for (int kt = 0; kt < 2; ++kt) {
                const s16x8 bfr = *(const s16x8*)(oT3 + (size_t)(ct * 16 + m) * R + kt * 32 + g * 8);
                aco = __builtin_amdgcn_mfma_f32_16x16x32_bf16(ap[kt], bfr, aco, 0, 0, 0);
            }
#pragma unroll
            for (int j = 0; j < 4; ++j)
                h4s[(g * 4 + j) * 132 + ct * 16 + m] = aco[j];
        }
    }
    __syncthreads();

    // ===== LayerNorm =====
    {
        const int rb = w * 4 + g;
        const int c0 = m * 8;
        const f32x4 v0 = *(const f32x4*)(h4s + rb * 132 + c0);
        const f32x4 v1 = *(const f32x4*)(h4s + rb * 132 + c0 + 4);
        float s  = v0[0] + v0[1] + v0[2] + v0[3] + v1[0] + v1[1] + v1[2] + v1[3];
        float ss = v0[0]*v0[0] + v0[1]*v0[1] + v0[2]*v0[2] + v0[3]*v0[3]
                 + v1[0]*v1[0] + v1[1]*v1[1] + v1[2]*v1[2] + v1[3]*v1[3];
#pragma unroll
        for (int off = 1; off < 16; off <<= 1) {
            s  += __shfl_xor(s, off);
            ss += __shfl_xor(ss, off);
        }
        const float mu   = s * (1.f / C);
        const float var  = ss * (1.f / C) - mu * mu;
        const float rstd = rsqrtf(var + 1e-5f);
        const f32x4 ga0 = *(const f32x4*)(gamma + c0);
        const f32x4 ga1 = *(const f32x4*)(gamma + c0 + 4);
        const f32x4 be0 = *(const f32x4*)(beta + c0);
        const f32x4 be1 = *(const f32x4*)(beta + c0 + 4);
        unsigned int o32[4];
        float hv[8];
#pragma unroll
        for (int k = 0; k < 4; ++k) hv[k]     = (v0[k] - mu) * rstd * ga0[k] + be0[k];
#pragma unroll
        for (int k = 0; k < 4; ++k) hv[4 + k] = (v1[k] - mu) * rstd * ga1[k] + be1[k];
#pragma unroll
        for (int k = 0; k < 4; ++k)
            o32[k] = (unsigned int)f2bf(hv[2*k]) | ((unsigned int)f2bf(hv[2*k+1]) << 16);
        *(uint4*)(hns + rb * 136 + c0) = *(uint4*)o32;
    }
    __syncthreads();

    // ===== Head GEMM + L2 norm =====
    {
        f32x4 acc[8];
#pragma unroll
        for (int nt = 0; nt < 8; ++nt) {
            const int e = w * 128 + nt * 16 + m;
            const float bv = bh[e];
            acc[nt] = (f32x4){bv, bv, bv, bv};
        }
#pragma unroll
        for (int kt = 0; kt < 4; ++kt) {
            const int koff = kt * 32 + g * 8;
            const s16x8 a = *(const s16x8*)(hns + m * 136 + koff);
#pragma unroll
            for (int nt = 0; nt < 8; ++nt) {
                const int e = w * 128 + nt * 16 + m;
                const s16x8 bfr = *(const s16x8*)(WhT + (size_t)e * 128 + koff);
                acc[nt] = __builtin_amdgcn_mfma_f32_16x16x32_bf16(a, bfr, acc[nt], 0, 0, 0);
            }
        }
        float sq[4];
#pragma unroll
        for (int j = 0; j < 4; ++j) {
            float s = 0.f;
#pragma unroll
            for (int nt = 0; nt < 8; ++nt) s += acc[nt][j] * acc[nt][j];
#pragma unroll
            for (int off = 1; off < 16; off <<= 1) s += __shfl_xor(s, off);
            sq[j] = s;
        }
        if (m == 0) {
#pragma unroll
            for (int j = 0; j < 4; ++j) red[(g * 4 + j) * 4 + w] = sq[j];
        }
        __syncthreads();
#pragma unroll
        for (int j = 0; j < 4; ++j) {
            const int row = g * 4 + j;
            const float tot = red[row * 4 + 0] + red[row * 4 + 1]
                            + red[row * 4 + 2] + red[row * 4 + 3];
            const float inv = 1.f / fmaxf(sqrtf(tot), 1e-12f);
#pragma unroll
            for (int nt = 0; nt < 8; ++nt) {
                const int e = w * 128 + nt * 16 + m;
                out[(size_t)(bt + row) * E + e] = acc[nt][j] * inv;
            }
        }
    }
}

// ---------------------------------------------------------------------------
extern "C" void kernel_launch(void* const* d_in, const int* in_sizes, int n_in,
                              void* d_out, int out_size, void* d_ws, size_t ws_size,
                              hipStream_t stream) {
    const float* x     = (const float*)d_in[0];
    const float* Wp    = (const float*)d_in[1];
    const float* bp    = (const float*)d_in[2];
    const float* pos   = (const float*)d_in[3];
    const float* gamma = (const float*)d_in[4];
    const float* beta  = (const float*)d_in[5];
    const float* Wh    = (const float*)d_in[6];
    const float* bh    = (const float*)d_in[7];
    const float* f0    = (const float*)d_in[8];
    const float* o0    = (const float*)d_in[9];
    const float* f1    = (const float*)d_in[10];
    const float* o1    = (const float*)d_in[11];
    const float* f2    = (const float*)d_in[12];
    const float* o2    = (const float*)d_in[13];
    const float* f3    = (const float*)d_in[14];
    const float* o3    = (const float*)d_in[15];
    float* out = (float*)d_out;

    // workspace layout (bf16 elements unless noted)
    unsigned short* h2  = (unsigned short*)d_ws;          // 1,048,576
    unsigned short* fTL = h2 + (size_t)1048576;           //   688,128 (84 slices)
    unsigned short* oT  = fTL + (size_t)688128;           //   696,320 (85 slices)
    unsigned short* WfT = oT + (size_t)696320;            // 1,048,576 (256 x 64x64)
    unsigned short* WhT = WfT + (size_t)1048576;          //    65,536
    float*          pff = (float*)(WhT + 65536);          //    16,384 fp32

    unsigned short* fT1 = fTL;
    unsigned short* fT2 = fTL + (size_t)64 * 8192;
    unsigned short* fT3 = fTL + (size_t)80 * 8192;
    unsigned short* oT2 = oT + (size_t)80 * 8192;
    unsigned short* oT3 = oT + (size_t)84 * 8192;

    prep_all_kernel<<<433, 256, 0, stream>>>(f0, f1, f2, f3, o0, o1, o2, o3,
                                             Wh, Wp, pos, bp,
                                             fTL, oT, WhT, WfT, pff);

    level01_fused<<<16 * 32, 256, 0, stream>>>(x, WfT, pff, oT, fT1, h2);

    tail_kernel<<<32, 256, 0, stream>>>(h2, fT2, oT2, fT3, oT3,
                                        gamma, beta, WhT, bh, out);
}

// Round 8
// 152.142 us; speedup vs baseline: 2.4750x; 1.0289x over previous
//
#include <hip/hip_runtime.h>
#include <hip/hip_bf16.h>

// Problem constants
#define BATCH     512
#define IMG       128
#define PS        8
#define GRID_P    16      // IMG/PS
#define NP        256     // GRID_P*GRID_P
#define C         128     // BOND_DIM
#define R         64      // CP_RANK
#define E         512     // EMBED_DIM

typedef float f32x4 __attribute__((ext_vector_type(4)));
typedef short s16x8 __attribute__((ext_vector_type(8)));

__device__ __forceinline__ unsigned short f2bf(float x) {
    unsigned int u = __float_as_uint(x);
    u += 0x7fffu + ((u >> 16) & 1u);          // RNE
    return (unsigned short)(u >> 16);
}
__device__ __forceinline__ float bf2f(unsigned short h) {
    return __uint_as_float(((unsigned int)h) << 16);
}

// ---------------------------------------------------------------------------
// prep_all (ONE launch, 433 blocks):
//   bi <256 : WfT+pf for level-0 slice (n0,q)=bi directly from f0 (in-LDS
//             transpose; fT0 never materialized).
//   bi 256..339 : f1/f2/f3 slices (128c x 64r) fp32 -> fTL (64r x 128c) bf16
//   bi 340..424 : o slices (64r x 128c) fp32 -> oT (128c x 64r) bf16
//   bi 425..432 : Wh (128c x 512e) -> WhT (512e x 128c) bf16
// ---------------------------------------------------------------------------
__global__ __launch_bounds__(256) void prep_all_kernel(
    const float* __restrict__ f0, const float* __restrict__ f1,
    const float* __restrict__ f2, const float* __restrict__ f3,
    const float* __restrict__ o0, const float* __restrict__ o1,
    const float* __restrict__ o2, const float* __restrict__ o3,
    const float* __restrict__ Wh, const float* __restrict__ Wp,
    const float* __restrict__ pos, const float* __restrict__ bp,
    unsigned short* __restrict__ fTL, unsigned short* __restrict__ oT,
    unsigned short* __restrict__ WhT, unsigned short* __restrict__ WfT,
    float* __restrict__ pf)
{
    __shared__ float ls[128 * 68];    // 34.8 KB
    __shared__ float red[64 * 4];
    const int bi = blockIdx.x, t = threadIdx.x;

    if (bi < 256) {
        const float* src = f0 + (size_t)bi * 8192;
#pragma unroll
        for (int i = 0; i < 8; ++i) {
            const int fi = (t + 256 * i) * 4;
            const int c = fi >> 6, r = fi & 63;      // in[c][r]
            *(float4*)(ls + c * 68 + r) = *(const float4*)(src + fi);
        }
        __syncthreads();

        const int w = t >> 6, lane = t & 63;
        const int m = lane & 15, g = lane >> 4;

        f32x4 acc[4];
#pragma unroll
        for (int nt = 0; nt < 4; ++nt) acc[nt] = (f32x4){0.f, 0.f, 0.f, 0.f};
#pragma unroll
        for (int kt = 0; kt < 4; ++kt) {
            s16x8 afr;
#pragma unroll
            for (int e = 0; e < 8; ++e)
                afr[e] = (short)f2bf(ls[(kt * 32 + g * 8 + e) * 68 + w * 16 + m]);
#pragma unroll
            for (int nt = 0; nt < 4; ++nt) {
                const float* wr = Wp + (size_t)(nt * 16 + m) * 128 + kt * 32 + g * 8;
                const float4 b0 = *(const float4*)wr;
                const float4 b1 = *(const float4*)(wr + 4);
                s16x8 bfr;
                bfr[0] = (short)f2bf(b0.x); bfr[1] = (short)f2bf(b0.y);
                bfr[2] = (short)f2bf(b0.z); bfr[3] = (short)f2bf(b0.w);
                bfr[4] = (short)f2bf(b1.x); bfr[5] = (short)f2bf(b1.y);
                bfr[6] = (short)f2bf(b1.z); bfr[7] = (short)f2bf(b1.w);
                acc[nt] = __builtin_amdgcn_mfma_f32_16x16x32_bf16(afr, bfr, acc[nt], 0, 0, 0);
            }
        }
        unsigned short* D = WfT + (size_t)bi * 4096;
#pragma unroll
        for (int nt = 0; nt < 4; ++nt)
#pragma unroll
            for (int j = 0; j < 4; ++j)
                D[(size_t)(w * 16 + g * 4 + j) * 64 + nt * 16 + m] = f2bf(acc[nt][j]);

        {
            const int r = t & 63, half = t >> 6;
            const int n0 = bi >> 2, q = bi & 3;
            const int pp = (2 * (n0 >> 3) + (q >> 1)) * GRID_P + 2 * (n0 & 7) + (q & 1);
            const float* posr = pos + (size_t)pp * C;
            float s = 0.f;
#pragma unroll 8
            for (int e = 0; e < 32; ++e) {
                const int c = half * 32 + e;
                s += (posr[c] + bp[c]) * ls[c * 68 + r];
            }
            red[r * 4 + half] = s;
        }
        __syncthreads();
        if (t < 64)
            pf[bi * 64 + t] = red[t * 4 + 0] + red[t * 4 + 1] + red[t * 4 + 2] + red[t * 4 + 3];
    } else if (bi < 340) {
        const int ti = bi - 256;
        const float* src;
        if      (ti < 64) src = f1 + (size_t)ti * 8192;
        else if (ti < 80) src = f2 + (size_t)(ti - 64) * 8192;
        else              src = f3 + (size_t)(ti - 80) * 8192;
        unsigned short* dst = fTL + (size_t)ti * 8192;
#pragma unroll
        for (int i = 0; i < 8; ++i) {
            const int fi = (t + 256 * i) * 4;
            const int c = fi >> 6, r = fi & 63;
            *(float4*)(ls + c * 68 + r) = *(const float4*)(src + fi);
        }
        __syncthreads();
        const int rr = t >> 2, seg = t & 3;
        unsigned int* d32 = (unsigned int*)(dst + rr * 128 + seg * 32);
#pragma unroll
        for (int ii = 0; ii < 16; ++ii) {
            const int c = seg * 32 + ii * 2;
            const unsigned int lo = f2bf(ls[c * 68 + rr]);
            const unsigned int hi = f2bf(ls[(c + 1) * 68 + rr]);
            d32[ii] = lo | (hi << 16);
        }
    } else if (bi < 425) {
        const int oi = bi - 340;
        const float* src;
        if      (oi < 64) src = o0 + (size_t)oi * 8192;
        else if (oi < 80) src = o1 + (size_t)(oi - 64) * 8192;
        else if (oi < 84) src = o2 + (size_t)(oi - 80) * 8192;
        else              src = o3 + (size_t)(oi - 84) * 8192;
        unsigned short* dst = oT + (size_t)oi * 8192;
#pragma unroll
        for (int i = 0; i < 8; ++i) {
            const int fi = (t + 256 * i) * 4;
            const int r = fi >> 7, c = fi & 127;
            *(float4*)(ls + r * 132 + c) = *(const float4*)(src + fi);
        }
        __syncthreads();
        const int cc = t >> 1, seg = t & 1;
        unsigned int* d32 = (unsigned int*)(dst + cc * 64 + seg * 32);
#pragma unroll
        for (int ii = 0; ii < 16; ++ii) {
            const int r = seg * 32 + ii * 2;
            const unsigned int lo = f2bf(ls[r * 132 + cc]);
            const unsigned int hi = f2bf(ls[(r + 1) * 132 + cc]);
            d32[ii] = lo | (hi << 16);
        }
    } else {
        const int j = bi - 425;
#pragma unroll
        for (int i = 0; i < 8; ++i) {
            const int fi = (t + 256 * i) * 4;
            const int c = fi >> 6, e = fi & 63;
            *(float4*)(ls + c * 68 + e) = *(const float4*)(Wh + (size_t)c * E + j * 64 + e);
        }
        __syncthreads();
        const int rr = t >> 2, seg = t & 3;
        unsigned int* d32 = (unsigned int*)(WhT + (size_t)(j * 64 + rr) * 128 + seg * 32);
#pragma unroll
        for (int ii = 0; ii < 16; ++ii) {
            const int c = seg * 32 + ii * 2;
            const unsigned int lo = f2bf(ls[c * 68 + rr]);
            const unsigned int hi = f2bf(ls[(c + 1) * 68 + rr]);
            d32[ii] = lo | (hi << 16);
        }
    }
}

// ---------------------------------------------------------------------------
// Fused level0+level1, v2: block-cooperative LDS pixel staging.
// Block = (n1, 16 batches) needs the 16 batches' 32x32 px region of n1 —
// 64 KB, 128B-line-aligned rows. Staged with 16 fully-coalesced float4
// iterations (8 lanes = 1 line), bf16-converted once, batch stride 1026
// shorts (513 dw == 1 mod 32 -> A-frag ds_read_b128 2-way banks = free).
// Then: wave w = child n0; level0 all in-wave; level1 via us1/ps1 barriers.
// ---------------------------------------------------------------------------
__global__ __launch_bounds__(256) void level01_fused(
    const float* __restrict__ x,              // (B,1,128,128)
    const unsigned short* __restrict__ WfT,   // 256 slices (64r x 64k)
    const float* __restrict__ pf,             // (256 x 64) fp32
    const unsigned short* __restrict__ oT,    // oT0 at slice n0, oT1 at 64+n1
    const unsigned short* __restrict__ fT1,   // 64 slices (64r x 128c)
    unsigned short* __restrict__ h2)          // (B,16,128) bf16
{
    __shared__ __align__(16) unsigned short pixs[16 * 1026];    // 32832 B
    __shared__ __align__(16) float          us1[4 * 16 * 68];   // 17408 B
    __shared__ __align__(16) unsigned short ps0[4 * 16 * 72];   //  9216 B
    __shared__ __align__(16) unsigned short ps1[16 * 72];       //  2304 B
    __shared__ __align__(16) unsigned short h1s[4 * 16 * 136];  // 17408 B

    const int bi = blockIdx.x;
    const int n1 = bi >> 5, btile = bi & 31;
    const int t = threadIdx.x, w = t >> 6, lane = t & 63;
    const int m = lane & 15, g = lane >> 4;
    const int bt = btile * 16;

    const int y1g = n1 >> 2, x1g = n1 & 3;
    const int Ry0 = y1g * 32, Rx0 = x1g * 32;
    const int n0 = (2 * y1g + (w >> 1)) * 8 + 2 * x1g + (w & 1);

    // ---- stage pixel region: 16 iters, fully line-coalesced ----
#pragma unroll
    for (int i = 0; i < 16; ++i) {
        const int idx = i * 256 + t;
        const int c4 = idx & 7, rowg = (idx >> 3) & 31, bl = idx >> 8;
        const float4 p4 = *(const float4*)(x + ((size_t)(bt + bl) * IMG + Ry0 + rowg) * IMG + Rx0 + c4 * 4);
        uint2 v;
        v.x = (unsigned int)f2bf(p4.x) | ((unsigned int)f2bf(p4.y) << 16);
        v.y = (unsigned int)f2bf(p4.z) | ((unsigned int)f2bf(p4.w) << 16);
        *(uint2*)(pixs + bl * 1026 + rowg * 32 + c4 * 4) = v;
    }
    __syncthreads();

    // ---- level0 pixel A-fragments from LDS ----
    s16x8 a[4][2];
    {
        const int rbase = 16 * (w >> 1);
        const int cbase = 16 * (w & 1);
#pragma unroll
        for (int q = 0; q < 4; ++q) {
            const int rq = rbase + 8 * (q >> 1) + g;
            const int cc = cbase + 8 * (q & 1);
#pragma unroll
            for (int kt = 0; kt < 2; ++kt)
                a[q][kt] = *(const s16x8*)(pixs + m * 1026 + (rq + kt * 4) * 32 + cc);
        }
    }

    // ---- level0 u-phase (+pf init), all 4 quadrants in-wave ----
    f32x4 accu[4][4];
#pragma unroll
    for (int q = 0; q < 4; ++q) {
        const float* pfq = pf + (size_t)(n0 * 4 + q) * 64;
#pragma unroll
        for (int nt = 0; nt < 4; ++nt) {
            const float pv = pfq[nt * 16 + m];
            accu[q][nt] = (f32x4){pv, pv, pv, pv};
        }
    }
#pragma unroll
    for (int q = 0; q < 4; ++q) {
        const unsigned short* Wq = WfT + (size_t)(n0 * 4 + q) * 4096;
#pragma unroll
        for (int kt = 0; kt < 2; ++kt) {
            const int koff = kt * 32 + g * 8;
#pragma unroll
            for (int nt = 0; nt < 4; ++nt) {
                const s16x8 bfr = *(const s16x8*)(Wq + (size_t)(nt * 16 + m) * 64 + koff);
                accu[q][nt] = __builtin_amdgcn_mfma_f32_16x16x32_bf16(a[q][kt], bfr, accu[q][nt], 0, 0, 0);
            }
        }
    }

    // ---- level0 p-phase (regs) + wave-private ps roundtrip ----
    unsigned short* myps = ps0 + w * (16 * 72);
#pragma unroll
    for (int nt = 0; nt < 4; ++nt) {
        const f32x4 pr = accu[0][nt] * accu[1][nt] * accu[2][nt] * accu[3][nt];
#pragma unroll
        for (int j = 0; j < 4; ++j)
            myps[(g * 4 + j) * 72 + nt * 16 + m] = f2bf(pr[j]);
    }

    // ---- level0 o-phase (in-wave) -> h1 tile in wave-private LDS ----
    {
        s16x8 ap[2];
#pragma unroll
        for (int kt = 0; kt < 2; ++kt)
            ap[kt] = *(const s16x8*)(myps + m * 72 + kt * 32 + g * 8);
        const unsigned short* oTn = oT + (size_t)n0 * 8192;
        unsigned short* myh = h1s + w * (16 * 136);
#pragma unroll
        for (int ct = 0; ct < 8; ++ct) {
            f32x4 aco = (f32x4){0.f, 0.f, 0.f, 0.f};
#pragma unroll
            for (int kt = 0; kt < 2; ++kt) {
                const s16x8 bfr = *(const s16x8*)(oTn + (size_t)(ct * 16 + m) * 64 + kt * 32 + g * 8);
                aco = __builtin_amdgcn_mfma_f32_16x16x32_bf16(ap[kt], bfr, aco, 0, 0, 0);
            }
#pragma unroll
            for (int j = 0; j < 4; ++j)
                myh[(g * 4 + j) * 136 + ct * 16 + m] = f2bf(aco[j]);
        }
    }

    // ---- level1 u-phase: A = own h1 tile (wave-private, no barrier) ----
    {
        const unsigned short* myh = h1s + w * (16 * 136);
        const unsigned short* fq = fT1 + (size_t)(n1 * 4 + w) * 8192;
        f32x4 au[4];
#pragma unroll
        for (int nt = 0; nt < 4; ++nt) au[nt] = (f32x4){0.f, 0.f, 0.f, 0.f};
#pragma unroll
        for (int kt = 0; kt < 4; ++kt) {
            const int koff = kt * 32 + g * 8;
            const s16x8 afr = *(const s16x8*)(myh + m * 136 + koff);
#pragma unroll
            for (int nt = 0; nt < 4; ++nt) {
                const s16x8 bfr = *(const s16x8*)(fq + (size_t)(nt * 16 + m) * 128 + koff);
                au[nt] = __builtin_amdgcn_mfma_f32_16x16x32_bf16(afr, bfr, au[nt], 0, 0, 0);
            }
        }
#pragma unroll
        for (int nt = 0; nt < 4; ++nt)
#pragma unroll
            for (int j = 0; j < 4; ++j)
                us1[(w * 16 + g * 4 + j) * 68 + nt * 16 + m] = au[nt][j];
    }
    __syncthreads();

    // ---- level1 p-phase (block-wide) ----
    {
        const int pb = t >> 4, r0 = (t & 15) * 4;
        const f32x4 u0 = *(const f32x4*)(us1 + (0 * 16 + pb) * 68 + r0);
        const f32x4 u1 = *(const f32x4*)(us1 + (1 * 16 + pb) * 68 + r0);
        const f32x4 u2 = *(const f32x4*)(us1 + (2 * 16 + pb) * 68 + r0);
        const f32x4 u3 = *(const f32x4*)(us1 + (3 * 16 + pb) * 68 + r0);
        const f32x4 p = u0 * u1 * u2 * u3;
        uint2 v;
        v.x = (unsigned int)f2bf(p[0]) | ((unsigned int)f2bf(p[1]) << 16);
        v.y = (unsigned int)f2bf(p[2]) | ((unsigned int)f2bf(p[3]) << 16);
        *(uint2*)(ps1 + pb * 72 + r0) = v;
    }
    __syncthreads();

    // ---- level1 o-phase: wave handles ct = 2w, 2w+1 -> h2 ----
    {
        s16x8 ap[2];
#pragma unroll
        for (int kt = 0; kt < 2; ++kt)
            ap[kt] = *(const s16x8*)(ps1 + m * 72 + kt * 32 + g * 8);
        const unsigned short* oTn = oT + (size_t)(64 + n1) * 8192;
#pragma unroll
        for (int i = 0; i < 2; ++i) {
            const int ct = w * 2 + i;
            f32x4 aco = (f32x4){0.f, 0.f, 0.f, 0.f};
#pragma unroll
            for (int kt = 0; kt < 2; ++kt) {
                const s16x8 bfr = *(const s16x8*)(oTn + (size_t)(ct * 16 + m) * 64 + kt * 32 + g * 8);
                aco = __builtin_amdgcn_mfma_f32_16x16x32_bf16(ap[kt], bfr, aco, 0, 0, 0);
            }
#pragma unroll
            for (int j = 0; j < 4; ++j)
                h2[((size_t)(bt + g * 4 + j) * 16 + n1) * C + ct * 16 + m] = f2bf(aco[j]);
        }
    }
}

// ---------------------------------------------------------------------------
// Tail: level2 + level3 + LayerNorm + head + L2norm, block = 16 batches.
// ---------------------------------------------------------------------------
__global__ __launch_bounds__(256) void tail_kernel(
    const unsigned short* __restrict__ h2,    // (B,16,128) bf16
    const unsigned short* __restrict__ fT2,   // 16 slices (64 x 128)
    const unsigned short* __restrict__ oT2,   // 4 slices (128 x 64)
    const unsigned short* __restrict__ fT3,   // 4 slices (64 x 128)
    const unsigned short* __restrict__ oT3,   // 1 slice (128 x 64)
    const float* __restrict__ gamma, const float* __restrict__ beta,
    const unsigned short* __restrict__ WhT,   // (512 x 128) bf16
    const float* __restrict__ bh,             // (512)
    float* __restrict__ out)                  // (B,512) fp32
{
    __shared__ __align__(16) float          us3[4 * 16 * 68];
    __shared__ __align__(16) unsigned short ps2[4 * 16 * 72];
    __shared__ __align__(16) unsigned short ps3[16 * 72];
    __shared__ __align__(16) unsigned short h3s[16 * 4 * 136];
    __shared__ __align__(16) float          h4s[16 * 132];
    __shared__ __align__(16) unsigned short hns[16 * 136];
    __shared__ float red[16 * 4];

    const int bt = blockIdx.x * 16;
    const int t = threadIdx.x, w = t >> 6, lane = t & 63;
    const int m = lane & 15, g = lane >> 4;

    // ===== Level 2: wave w = node n2 =====
    {
        const int n2 = w;
        const int y1 = n2 >> 1, x1 = n2 & 1;
        f32x4 acc_u[4][4];
#pragma unroll
        for (int q = 0; q < 4; ++q)
#pragma unroll
            for (int nt = 0; nt < 4; ++nt) acc_u[q][nt] = (f32x4){0.f, 0.f, 0.f, 0.f};
#pragma unroll
        for (int q = 0; q < 4; ++q) {
            const int pidx = (2 * y1 + (q >> 1)) * 4 + 2 * x1 + (q & 1);
            const unsigned short* xq = h2 + ((size_t)(bt + m) * 16 + pidx) * C;
            const unsigned short* fq = fT2 + (size_t)(n2 * 4 + q) * R * C;
#pragma unroll
            for (int kt = 0; kt < 4; ++kt) {
                const int koff = kt * 32 + g * 8;
                const s16x8 a = *(const s16x8*)(xq + koff);
#pragma unroll
                for (int nt = 0; nt < 4; ++nt) {
                    const s16x8 bfr = *(const s16x8*)(fq + (size_t)(nt * 16 + m) * C + koff);
                    acc_u[q][nt] = __builtin_amdgcn_mfma_f32_16x16x32_bf16(a, bfr, acc_u[q][nt], 0, 0, 0);
                }
            }
        }
        unsigned short* myps = ps2 + w * 16 * 72;
#pragma unroll
        for (int nt = 0; nt < 4; ++nt) {
            const f32x4 p = acc_u[0][nt] * acc_u[1][nt] * acc_u[2][nt] * acc_u[3][nt];
#pragma unroll
            for (int j = 0; j < 4; ++j)
                myps[(g * 4 + j) * 72 + nt * 16 + m] = f2bf(p[j]);
        }
        f32x4 aco[8];
#pragma unroll
        for (int ct = 0; ct < 8; ++ct) aco[ct] = (f32x4){0.f, 0.f, 0.f, 0.f};
        const unsigned short* oTn = oT2 + (size_t)n2 * C * R;
#pragma unroll
        for (int kt = 0; kt < 2; ++kt) {
            const int koff = kt * 32 + g * 8;
            const s16x8 a = *(const s16x8*)(myps + m * 72 + koff);
#pragma unroll
            for (int ct = 0; ct < 8; ++ct) {
                const s16x8 bfr = *(const s16x8*)(oTn + (size_t)(ct * 16 + m) * R + koff);
                aco[ct] = __builtin_amdgcn_mfma_f32_16x16x32_bf16(a, bfr, aco[ct], 0, 0, 0);
            }
        }
#pragma unroll
        for (int ct = 0; ct < 8; ++ct)
#pragma unroll
            for (int j = 0; j < 4; ++j)
                h3s[((g * 4 + j) * 4 + n2) * 136 + ct * 16 + m] = f2bf(aco[ct][j]);
    }
    __syncthreads();

    // ===== Level 3: wave w = quadrant q =====
    {
        const int q = w;
        const unsigned short* fq = fT3 + (size_t)q * R * C;
        f32x4 acc_u[4];
#pragma unroll
        for (int nt = 0; nt < 4; ++nt) acc_u[nt] = (f32x4){0.f, 0.f, 0.f, 0.f};
#pragma unroll
        for (int kt = 0; kt < 4; ++kt) {
            const int koff = kt * 32 + g * 8;
            const s16x8 a = *(const s16x8*)(h3s + (m * 4 + q) * 136 + koff);
#pragma unroll
            for (int nt = 0; nt < 4; ++nt) {
                const s16x8 bfr = *(const s16x8*)(fq + (size_t)(nt * 16 + m) * C + koff);
                acc_u[nt] = __builtin_amdgcn_mfma_f32_16x16x32_bf16(a, bfr, acc_u[nt], 0, 0, 0);
            }
        }
#pragma unroll
        for (int nt = 0; nt < 4; ++nt)
#pragma unroll
            for (int j = 0; j < 4; ++j)
                us3[(q * 16 + g * 4 + j) * 68 + nt * 16 + m] = acc_u[nt][j];
    }
    __syncthreads();
    {
        const int pb = t >> 4, r0 = (t & 15) * 4;
        const f32x4 u0 = *(const f32x4*)(us3 + (0 * 16 + pb) * 68 + r0);
        const f32x4 u1 = *(const f32x4*)(us3 + (1 * 16 + pb) * 68 + r0);
        const f32x4 u2 = *(const f32x4*)(us3 + (2 * 16 + pb) * 68 + r0);
        const f32x4 u3 = *(const f32x4*)(us3 + (3 * 16 + pb) * 68 + r0);
        const f32x4 p = u0 * u1 * u2 * u3;
        uint2 v;
        v.x = (unsigned int)f2bf(p[0]) | ((unsigned int)f2bf(p[1]) << 16);
        v.y = (unsigned int)f2bf(p[2]) | ((unsigned int)f2bf(p[3]) << 16);
        *(uint2*)(ps3 + pb * 72 + r0) = v;
    }
    __syncthreads();
    {
        s16x8 ap[2];
#pragma unroll
        for (int kt = 0; kt < 2; ++kt)
            ap[kt] = *(const s16x8*)(ps3 + m * 72 + kt * 32 + g * 8);
#pragma unroll
        for (int i = 0; i < 2; ++i) {
            f32x4 aco = (f32x4){0.f, 0.f, 0.f, 0.f};
            const int ct = w * 2 + i;
#pragma unroll
            for (int kt = 0; kt < 2; ++kt) {
                const s16x8 bfr = *(const s16x8*)(oT3 + (size_t)(ct * 16 + m) * R + kt * 32 + g * 8);
                aco = __builtin_amdgcn_mfma_f32_16x16x32_bf16(ap[kt], bfr, aco, 0, 0, 0);
            }
#pragma unroll
            for (int j = 0; j < 4; ++j)
                h4s[(g * 4 + j) * 132 + ct * 16 + m] = aco[j];
        }
    }
    __syncthreads();

    // ===== LayerNorm =====
    {
        const int rb = w * 4 + g;
        const int c0 = m * 8;
        const f32x4 v0 = *(const f32x4*)(h4s + rb * 132 + c0);
        const f32x4 v1 = *(const f32x4*)(h4s + rb * 132 + c0 + 4);
        float s  = v0[0] + v0[1] + v0[2] + v0[3] + v1[0] + v1[1] + v1[2] + v1[3];
        float ss = v0[0]*v0[0] + v0[1]*v0[1] + v0[2]*v0[2] + v0[3]*v0[3]
                 + v1[0]*v1[0] + v1[1]*v1[1] + v1[2]*v1[2] + v1[3]*v1[3];
#pragma unroll
        for (int off = 1; off < 16; off <<= 1) {
            s  += __shfl_xor(s, off);
            ss += __shfl_xor(ss, off);
        }
        const float mu   = s * (1.f / C);
        const float var  = ss * (1.f / C) - mu * mu;
        const float rstd = rsqrtf(var + 1e-5f);
        const f32x4 ga0 = *(const f32x4*)(gamma + c0);
        const f32x4 ga1 = *(const f32x4*)(gamma + c0 + 4);
        const f32x4 be0 = *(const f32x4*)(beta + c0);
        const f32x4 be1 = *(const f32x4*)(beta + c0 + 4);
        unsigned int o32[4];
        float hv[8];
#pragma unroll
        for (int k = 0; k < 4; ++k) hv[k]     = (v0[k] - mu) * rstd * ga0[k] + be0[k];
#pragma unroll
        for (int k = 0; k < 4; ++k) hv[4 + k] = (v1[k] - mu) * rstd * ga1[k] + be1[k];
#pragma unroll
        for (int k = 0; k < 4; ++k)
            o32[k] = (unsigned int)f2bf(hv[2*k]) | ((unsigned int)f2bf(hv[2*k+1]) << 16);
        *(uint4*)(hns + rb * 136 + c0) = *(uint4*)o32;
    }
    __syncthreads();

    // ===== Head GEMM + L2 norm =====
    {
        f32x4 acc[8];
#pragma unroll
        for (int nt = 0; nt < 8; ++nt) {
            const int e = w * 128 + nt * 16 + m;
            const float bv = bh[e];
            acc[nt] = (f32x4){bv, bv, bv, bv};
        }
#pragma unroll
        for (int kt = 0; kt < 4; ++kt) {
            const int koff = kt * 32 + g * 8;
            const s16x8 a = *(const s16x8*)(hns + m * 136 + koff);
#pragma unroll
            for (int nt = 0; nt < 8; ++nt) {
                const int e = w * 128 + nt * 16 + m;
                const s16x8 bfr = *(const s16x8*)(WhT + (size_t)e * 128 + koff);
                acc[nt] = __builtin_amdgcn_mfma_f32_16x16x32_bf16(a, bfr, acc[nt], 0, 0, 0);
            }
        }
        float sq[4];
#pragma unroll
        for (int j = 0; j < 4; ++j) {
            float s = 0.f;
#pragma unroll
            for (int nt = 0; nt < 8; ++nt) s += acc[nt][j] * acc[nt][j];
#pragma unroll
            for (int off = 1; off < 16; off <<= 1) s += __shfl_xor(s, off);
            sq[j] = s;
        }
        if (m == 0) {
#pragma unroll
            for (int j = 0; j < 4; ++j) red[(g * 4 + j) * 4 + w] = sq[j];
        }
        __syncthreads();
#pragma unroll
        for (int j = 0; j < 4; ++j) {
            const int row = g * 4 + j;
            const float tot = red[row * 4 + 0] + red[row * 4 + 1]
                            + red[row * 4 + 2] + red[row * 4 + 3];
            const float inv = 1.f / fmaxf(sqrtf(tot), 1e-12f);
#pragma unroll
            for (int nt = 0; nt < 8; ++nt) {
                const int e = w * 128 + nt * 16 + m;
                out[(size_t)(bt + row) * E + e] = acc[nt][j] * inv;
            }
        }
    }
}

// ---------------------------------------------------------------------------
extern "C" void kernel_launch(void* const* d_in, const int* in_sizes, int n_in,
                              void* d_out, int out_size, void* d_ws, size_t ws_size,
                              hipStream_t stream) {
    const float* x     = (const float*)d_in[0];
    const float* Wp    = (const float*)d_in[1];
    const float* bp    = (const float*)d_in[2];
    const float* pos   = (const float*)d_in[3];
    const float* gamma = (const float*)d_in[4];
    const float* beta  = (const float*)d_in[5];
    const float* Wh    = (const float*)d_in[6];
    const float* bh    = (const float*)d_in[7];
    const float* f0    = (const float*)d_in[8];
    const float* o0    = (const float*)d_in[9];
    const float* f1    = (const float*)d_in[10];
    const float* o1    = (const float*)d_in[11];
    const float* f2    = (const float*)d_in[12];
    const float* o2    = (const float*)d_in[13];
    const float* f3    = (const float*)d_in[14];
    const float* o3    = (const float*)d_in[15];
    float* out = (float*)d_out;

    // workspace layout (bf16 elements unless noted)
    unsigned short* h2  = (unsigned short*)d_ws;          // 1,048,576
    unsigned short* fTL = h2 + (size_t)1048576;           //   688,128 (84 slices)
    unsigned short* oT  = fTL + (size_t)688128;           //   696,320 (85 slices)
    unsigned short* WfT = oT + (size_t)696320;            // 1,048,576 (256 x 64x64)
    unsigned short* WhT = WfT + (size_t)1048576;          //    65,536
    float*          pff = (float*)(WhT + 65536);          //    16,384 fp32

    unsigned short* fT1 = fTL;
    unsigned short* fT2 = fTL + (size_t)64 * 8192;
    unsigned short* fT3 = fTL + (size_t)80 * 8192;
    unsigned short* oT2 = oT + (size_t)80 * 8192;
    unsigned short* oT3 = oT + (size_t)84 * 8192;

    prep_all_kernel<<<433, 256, 0, stream>>>(f0, f1, f2, f3, o0, o1, o2, o3,
                                             Wh, Wp, pos, bp,
                                             fTL, oT, WhT, WfT, pff);

    level01_fused<<<16 * 32, 256, 0, stream>>>(x, WfT, pff, oT, fT1, h2);

    tail_kernel<<<32, 256, 0, stream>>>(h2, fT2, oT2, fT3, oT3,
                                        gamma, beta, WhT, bh, out);
}